// Round 1
// baseline (95029.999 us; speedup 1.0000x reference)
//
#include <hip/hip_runtime.h>
#include <math.h>

// ---------------------------------------------------------------------------
// SimAM-CNN + Mogrifier-LSTM (Round 3): persistent cooperative LSTM kernel.
// B=128, T=128, D=64; CNN 1->32->32(3x3)->SimAM->(1x1)64->64(3x3)->SimAM;
// LSTM IN=4096,H=256, 128 steps, 3 mogrifier rounds; FC->5.
// xl[b,t,:] is the flat NCHW reinterpret of z: z + b*524288 + t*4096.
// LSTM runs as ONE kernel: 256 blocks x 1024 threads (1 block/CU), 8 grid
// barriers per timestep (hand-rolled device-scope barrier), hmfin fused into
// the next matmul stage's LDS fill.
// ---------------------------------------------------------------------------

typedef unsigned short u16;

#define EPSBN 1e-5f

__device__ __forceinline__ float sigf(float x) { return 1.0f / (1.0f + expf(-x)); }

__device__ __forceinline__ float b2f(u16 u) {
  union { unsigned int i; float f; } v; v.i = ((unsigned int)u) << 16; return v.f;
}
__device__ __forceinline__ u16 f2b(float f) {
  union { float f; unsigned int i; } v; v.f = f;
  unsigned int r = v.i + 0x7FFFu + ((v.i >> 16) & 1u);
  return (u16)(r >> 16);
}

template <typename T> __device__ __forceinline__ float ld1(const T* p);
template <> __device__ __forceinline__ float ld1<float>(const float* p) { return *p; }
template <> __device__ __forceinline__ float ld1<u16>(const u16* p) { return b2f(*p); }
template <typename T> __device__ __forceinline__ void st1(T* p, float v);
template <> __device__ __forceinline__ void st1<float>(float* p, float v) { *p = v; }
template <> __device__ __forceinline__ void st1<u16>(u16* p, float v) { *p = f2b(v); }

__device__ __forceinline__ float simam_elem(float xv, float s, float ss) {
  float mu = (s - xv) * (1.0f / 8191.0f);
  float var = (ss - xv * xv - 8191.0f * mu * mu) * (1.0f / 8190.0f);
  float einv = ((xv - mu) * (xv - mu) + 2.0f * var + 0.2f) / (4.0f * (var + 0.1f));
  return xv * sigf(einv);
}

// --------------------------- CNN stage 1 -----------------------------------
__global__ __launch_bounds__(256) void k_conv1(
    const float* __restrict__ x,
    const float* __restrict__ w1a, const float* __restrict__ b1a,
    const float* __restrict__ g1a, const float* __restrict__ bb1a,
    const float* __restrict__ m1a, const float* __restrict__ v1a,
    const float* __restrict__ w1b, const float* __restrict__ b1b,
    const float* __restrict__ g1b, const float* __restrict__ bb1b,
    const float* __restrict__ m1b, const float* __restrict__ v1b,
    u16* __restrict__ y1u, float* __restrict__ ps1, float* __restrict__ pss1)
{
  __shared__ float xs[6][66];
  __shared__ float a1[32][6][66];
  __shared__ float A1[32], T1[32], S2[32], T2[32];
  __shared__ float reds[4][32], redq[4][32];
  const int tid = threadIdx.x;
  const int b = blockIdx.x, t0 = blockIdx.y * 4;
  if (tid < 32) {
    float s = g1a[tid] * rsqrtf(v1a[tid] + EPSBN);
    A1[tid] = w1a[tid] * s;
    T1[tid] = (b1a[tid] - m1a[tid]) * s + bb1a[tid];
    float s2 = g1b[tid] * rsqrtf(v1b[tid] + EPSBN);
    S2[tid] = s2;
    T2[tid] = (b1b[tid] - m1b[tid]) * s2 + bb1b[tid];
  }
  for (int i = tid; i < 6 * 66; i += 256) {
    int r = i / 66, cc = i - r * 66;
    int t = t0 + r - 1, d = cc - 1;
    float v = 0.f;
    if (t >= 0 && t < 128 && d >= 0 && d < 64) v = x[(b * 128 + t) * 64 + d];
    xs[r][cc] = v;
  }
  __syncthreads();
  for (int i = tid; i < 32 * 6 * 66; i += 256) {
    int c = i / 396;
    int rr = i - c * 396;
    int r = rr / 66, cc = rr - r * 66;
    int t = t0 + r - 1, d = cc - 1;
    float v = 0.f;
    if (t >= 0 && t < 128 && d >= 0 && d < 64)
      v = fmaxf(xs[r][cc] * A1[c] + T1[c], 0.f);
    a1[c][r][cc] = v;
  }
  __syncthreads();
  const int d = tid & 63, tq = tid >> 6, lane = tid & 63;
  float acc[32];
#pragma unroll
  for (int i = 0; i < 32; ++i) acc[i] = 0.f;
#pragma unroll 1
  for (int c1 = 0; c1 < 32; ++c1) {
#pragma unroll
    for (int dt = 0; dt < 3; ++dt) {
      float av0 = a1[c1][tq + dt][d];
      float av1 = a1[c1][tq + dt][d + 1];
      float av2 = a1[c1][tq + dt][d + 2];
#pragma unroll
      for (int c2 = 0; c2 < 32; ++c2) {
        const float* wp = w1b + ((c2 * 32 + c1) * 3 + dt) * 3;  // uniform
        acc[c2] += av0 * wp[0] + av1 * wp[1] + av2 * wp[2];
      }
    }
  }
  const size_t ob = (size_t)b * 32 * 8192 + (size_t)(t0 + tq) * 64 + d;
#pragma unroll
  for (int c2 = 0; c2 < 32; ++c2) {
    float v = fmaxf(acc[c2] * S2[c2] + T2[c2], 0.f);
    y1u[ob + (size_t)c2 * 8192] = f2b(v);
    float s = v, q = v * v;
#pragma unroll
    for (int off = 32; off; off >>= 1) {
      s += __shfl_down(s, off);
      q += __shfl_down(q, off);
    }
    if (lane == 0) { reds[tq][c2] = s; redq[tq][c2] = q; }
  }
  __syncthreads();
  if (tid < 32) {
    float s = (reds[0][tid] + reds[1][tid]) + (reds[2][tid] + reds[3][tid]);
    float q = (redq[0][tid] + redq[1][tid]) + (redq[2][tid] + redq[3][tid]);
    ps1[(size_t)((b * 32 + tid) << 5) + blockIdx.y] = s;
    pss1[(size_t)((b * 32 + tid) << 5) + blockIdx.y] = q;
  }
}

__global__ __launch_bounds__(256) void k_red(
    const float* __restrict__ ps, const float* __restrict__ pss,
    float* __restrict__ stats, int npart, int nplanes)
{
  int p = blockIdx.x * 256 + threadIdx.x;
  if (p >= nplanes) return;
  float s = 0.f, q = 0.f;
  for (int j = 0; j < npart; ++j) {
    s += ps[(size_t)p * npart + j];
    q += pss[(size_t)p * npart + j];
  }
  stats[p] = s;
  stats[nplanes + p] = q;
}

template <typename T>
__global__ __launch_bounds__(256) void k_simam_t(
    T* __restrict__ buf, const float* __restrict__ stats, int nplanes)
{
  const int p = blockIdx.x, tid = threadIdx.x;
  T* base = buf + (size_t)p * 8192;
  const float s = stats[p], ss = stats[nplanes + p];
#pragma unroll 4
  for (int i = 0; i < 32; ++i) {
    int idx = tid + i * 256;
    float v = ld1(base + idx);
    st1(base + idx, simam_elem(v, s, ss));
  }
}

// --------------------------- CNN stage 2 -----------------------------------
template <typename ZT>
__global__ __launch_bounds__(256) void k_conv2(
    const u16* __restrict__ y1u,
    const float* __restrict__ w2a, const float* __restrict__ b2a,
    const float* __restrict__ g2a, const float* __restrict__ bb2a,
    const float* __restrict__ m2a, const float* __restrict__ v2a,
    const float* __restrict__ w2b, const float* __restrict__ b2b,
    const float* __restrict__ g2b, const float* __restrict__ bb2b,
    const float* __restrict__ m2b, const float* __restrict__ v2b,
    ZT* __restrict__ z, float* __restrict__ ps2, float* __restrict__ pss2)
{
  __shared__ float y1s[32][4][66];
  __shared__ float a2[64][4][66];
  __shared__ float sA2a[64], sT2a[64], sA2b[64], sT2b[64];
  const int tid = threadIdx.x;
  const int t0 = blockIdx.x * 2, b = blockIdx.y;
  if (tid < 64) {
    float sa = g2a[tid] * rsqrtf(v2a[tid] + EPSBN);
    sA2a[tid] = sa;
    sT2a[tid] = (b2a[tid] - m2a[tid]) * sa + bb2a[tid];
    float sb = g2b[tid] * rsqrtf(v2b[tid] + EPSBN);
    sA2b[tid] = sb;
    sT2b[tid] = (b2b[tid] - m2b[tid]) * sb + bb2b[tid];
  }
  for (int i = tid; i < 32 * 4 * 66; i += 256) {
    int c1 = i / 264;
    int rr = i - c1 * 264;
    int r = rr / 66, cc = rr - r * 66;
    int t = t0 + r - 1, dd = cc - 1;
    float v = 0.f;
    if (t >= 0 && t < 128 && dd >= 0 && dd < 64)
      v = b2f(y1u[(size_t)(b * 32 + c1) * 8192 + t * 64 + dd]);
    y1s[c1][r][cc] = v;
  }
  __syncthreads();
  const int lane = tid & 63;
  const int c2base = __builtin_amdgcn_readfirstlane((int)(tid >> 6)) * 16;
#pragma unroll 1
  for (int i = 0; i < 16; ++i) {
    const int c2 = c2base + i;
    const float* wp = w2a + c2 * 32;  // uniform
    const float scl = sA2a[c2], off = sT2a[c2];
#pragma unroll 1
    for (int r = 0; r < 4; ++r) {
      for (int cc = lane; cc < 66; cc += 64) {
        float acc = 0.f;
#pragma unroll
        for (int c1 = 0; c1 < 32; ++c1) acc += y1s[c1][r][cc] * wp[c1];
        int t = t0 + r - 1, dd = cc - 1;
        float val = 0.f;
        if (t >= 0 && t < 128 && dd >= 0 && dd < 64)
          val = fmaxf(acc * scl + off, 0.f);
        a2[c2][r][cc] = val;
      }
    }
  }
  __syncthreads();
  const int d = tid & 63;
  const int gq = __builtin_amdgcn_readfirstlane((int)(tid >> 6));
  float acc[16][2];
#pragma unroll
  for (int i = 0; i < 16; ++i) { acc[i][0] = 0.f; acc[i][1] = 0.f; }
#pragma unroll 1
  for (int c1 = 0; c1 < 64; ++c1) {
    float a00 = a2[c1][0][d], a01 = a2[c1][0][d + 1], a02 = a2[c1][0][d + 2];
    float a10 = a2[c1][1][d], a11 = a2[c1][1][d + 1], a12 = a2[c1][1][d + 2];
    float a20 = a2[c1][2][d], a21 = a2[c1][2][d + 1], a22 = a2[c1][2][d + 2];
    float a30 = a2[c1][3][d], a31 = a2[c1][3][d + 1], a32 = a2[c1][3][d + 2];
#pragma unroll
    for (int i = 0; i < 16; ++i) {
      const float* wp = w2b + (size_t)((gq * 16 + i) * 64 + c1) * 9;  // uniform
      float w0 = wp[0], w1 = wp[1], w2 = wp[2];
      float w3 = wp[3], w4 = wp[4], w5 = wp[5];
      float w6 = wp[6], w7 = wp[7], w8 = wp[8];
      acc[i][0] += a00 * w0 + a01 * w1 + a02 * w2 + a10 * w3 + a11 * w4 +
                   a12 * w5 + a20 * w6 + a21 * w7 + a22 * w8;
      acc[i][1] += a10 * w0 + a11 * w1 + a12 * w2 + a20 * w3 + a21 * w4 +
                   a22 * w5 + a30 * w6 + a31 * w7 + a32 * w8;
    }
  }
#pragma unroll
  for (int i = 0; i < 16; ++i) {
    int c2 = gq * 16 + i;
    float sc = sA2b[c2], tb = sT2b[c2];
    float v0 = fmaxf(acc[i][0] * sc + tb, 0.f);
    float v1 = fmaxf(acc[i][1] * sc + tb, 0.f);
    size_t ob = (size_t)(b * 64 + c2) * 8192 + (size_t)t0 * 64 + d;
    st1(z + ob, v0);
    st1(z + ob + 64, v1);
    float s = v0 + v1, q = v0 * v0 + v1 * v1;
#pragma unroll
    for (int off = 32; off; off >>= 1) {
      s += __shfl_down(s, off);
      q += __shfl_down(q, off);
    }
    if (lane == 0) {
      ps2[(size_t)((b * 64 + c2) << 6) + blockIdx.x] = s;
      pss2[(size_t)((b * 64 + c2) << 6) + blockIdx.x] = q;
    }
  }
}

// --------------------------- persistent LSTM -------------------------------
// grid barrier: monotone arrive counter + release word (both zeroed by a
// captured hipMemsetAsync before launch). All 256 blocks are co-resident
// (cooperative launch; 1 block/CU at 1024 thr, 32KB LDS, <=128 VGPR).
__device__ __forceinline__ void gbar(unsigned* cnt, unsigned* rel, unsigned gen) {
  __syncthreads();
  if (threadIdx.x == 0) {
    __threadfence();  // release: flush this XCD's dirty lines device-wide
    unsigned prev = __hip_atomic_fetch_add(cnt, 1u, __ATOMIC_ACQ_REL,
                                           __HIP_MEMORY_SCOPE_AGENT);
    if (prev == gen * 256u - 1u) {
      __hip_atomic_store(rel, gen, __ATOMIC_RELEASE, __HIP_MEMORY_SCOPE_AGENT);
    } else {
      while (__hip_atomic_load(rel, __ATOMIC_ACQUIRE,
                               __HIP_MEMORY_SCOPE_AGENT) < gen) {
        __builtin_amdgcn_s_sleep(8);
      }
    }
    __threadfence();  // acquire: invalidate stale L1/L2 lines
  }
  __syncthreads();
  asm volatile("" ::: "memory");
}

struct LPar {
  const void* z;
  const float* qw0; const float* qb0; const float* rw0; const float* rb0;
  const float* qw1; const float* qb1; const float* rw1; const float* rb1;
  const float* qw2; const float* qb2; const float* rw2; const float* rb2;
  const float* wih; const float* whh; const float* bih; const float* bhh;
  const float* fcw; const float* fcb;
  float* xm; float* h; float* c; float* hmA; float* hmB;
  float* rslab; float* gslab;
  unsigned* cnt; unsigned* rel;
  float* out;
};

// 256 blocks x 1024 threads, 1 block/CU (4 waves/SIMD).
// Per step (8 grid barriers):
//   hfin | q0 | r0 | q1(+hmfin0->hmA) | r1 | q2(+hmfin1->hmB) | r2 |
//   gates: wih (all blocks) + whh (bid<128, fused hmfin2 from rslab+hmB)
template <typename ZT>
__global__ __launch_bounds__(1024, 4) void k_lstm(LPar p)
{
  __shared__ float sm[8192];  // 32 KB, reused per stage
  const int tid = threadIdx.x;
  const int bid = blockIdx.x;
  unsigned gen = 0;

  for (int t = 0; t <= 128; ++t) {
    // ---- hfin: h,c from gslab(t-1) ----
    if (bid < 32) {
      const int i = (bid << 10) + tid;
      const int b = i >> 8, k = i & 255;
      if (t == 0) {
        p.h[i] = 0.f; p.c[i] = 0.f;
      } else {
        float gi = p.bih[k]       + p.bhh[k];
        float gf = p.bih[k + 256] + p.bhh[k + 256];
        float gg = p.bih[k + 512] + p.bhh[k + 512];
        float go = p.bih[k + 768] + p.bhh[k + 768];
#pragma unroll 1
        for (int s = 0; s < 17; ++s) {
          const float* gs = p.gslab + (size_t)s * 131072 + b * 1024;
          gi += gs[k]; gf += gs[k + 256]; gg += gs[k + 512]; go += gs[k + 768];
        }
        float cn = sigf(gf) * p.c[i] + sigf(gi) * tanhf(gg);
        p.c[i] = cn;
        p.h[i] = sigf(go) * tanhf(cn);
      }
    }
    gbar(p.cnt, p.rel, ++gen);
    if (t == 128) break;

    const int qnt = bid & 63, qbt = bid >> 6;  // 64 n-tiles x 4 b-tiles
    const int qb0 = qbt * 32;

#pragma unroll 1
    for (int s = 0; s < 3; ++s) {
      // ---- q stage (s>0 fuses hmfin(s-1) into the LDS fill) ----
      {
        if (s == 0) {
          for (int i = tid; i < 8192; i += 1024)
            sm[i] = p.h[(qb0 << 8) + i];
        } else {
          const float* rbv = (s == 1) ? p.rb0 : p.rb1;
          const float* src = (s == 1) ? p.h : p.hmA;
          for (int i = tid; i < 8192; i += 1024) {
            const int bl = i >> 8, k = i & 255;
            const int b = qb0 + bl;
            float acc = rbv[k];
#pragma unroll
            for (int ss = 0; ss < 8; ++ss)
              acc += p.rslab[(size_t)((ss * 128 + b) << 8) + k];
            sm[i] = 2.0f * sigf(acc) * src[(b << 8) + k];
          }
        }
        __syncthreads();
        if (s > 0 && qnt == 0) {  // 4 blocks store hm chunk for later stages
          float* dst = (s == 1) ? p.hmA : p.hmB;
          for (int i = tid; i < 8192; i += 1024)
            dst[(qb0 << 8) + i] = sm[i];
        }
        const float* qW = (s == 0) ? p.qw0 : ((s == 1) ? p.qw1 : p.qw2);
        const float* qB = (s == 0) ? p.qb0 : ((s == 1) ? p.qb1 : p.qb2);
        const int n = (qnt << 6) + (tid & 63);
        const int bg = tid >> 6;  // 0..15, rows bg*2, bg*2+1
        const float* wrow = qW + (size_t)n * 256;
        const float* h0 = &sm[(bg * 2) << 8];
        const float* h1 = &sm[(bg * 2 + 1) << 8];
        float acc0 = 0.f, acc1 = 0.f;
        for (int k = 0; k < 256; k += 4) {
          float4 w  = *(const float4*)(wrow + k);
          float4 a4 = *(const float4*)(h0 + k);
          float4 b4 = *(const float4*)(h1 + k);
          acc0 += w.x * a4.x + w.y * a4.y + w.z * a4.z + w.w * a4.w;
          acc1 += w.x * b4.x + w.y * b4.y + w.z * b4.z + w.w * b4.w;
        }
        const float bias = qB[n];
        const int b_0 = qb0 + bg * 2, b_1 = b_0 + 1;
        float xv0, xv1;
        if (s == 0) {
          const ZT* zz = (const ZT*)p.z;
          xv0 = ld1(zz + (size_t)b_0 * 524288 + t * 4096 + n);
          xv1 = ld1(zz + (size_t)b_1 * 524288 + t * 4096 + n);
        } else {
          xv0 = p.xm[(size_t)b_0 * 4096 + n];
          xv1 = p.xm[(size_t)b_1 * 4096 + n];
        }
        p.xm[(size_t)b_0 * 4096 + n] = 2.0f * sigf(acc0 + bias) * xv0;
        p.xm[(size_t)b_1 * 4096 + n] = 2.0f * sigf(acc1 + bias) * xv1;
      }
      gbar(p.cnt, p.rel, ++gen);
      // ---- r stage: rslab[ks][b][n] partials, K split 8x512 ----
      {
        const float* rW = (s == 0) ? p.rw0 : ((s == 1) ? p.rw1 : p.rw2);
        const int nt = bid & 7, bt = (bid >> 3) & 3, ks = bid >> 5;
        const int n = (nt << 5) + (tid & 31);
        const int b0 = bt * 32, bg = tid >> 5;  // 0..31, one b-row each
        const float* wrow = rW + (size_t)n * 4096;
        float acc = 0.f;
#pragma unroll 1
        for (int sub = 0; sub < 4; ++sub) {
          const int kbase = (ks << 9) + (sub << 7);
          __syncthreads();
          {
            const int row = tid >> 5, col4 = tid & 31;  // 1024 float4 = tile
            *(float4*)&sm[(row << 7) + (col4 << 2)] =
                *(const float4*)(p.xm + (size_t)(b0 + row) * 4096 + kbase +
                                 (col4 << 2));
          }
          __syncthreads();
          const float* xr = &sm[bg << 7];
          for (int k = 0; k < 128; k += 4) {
            float4 w  = *(const float4*)(wrow + kbase + k);
            float4 xv = *(const float4*)(xr + k);
            acc += w.x * xv.x + w.y * xv.y + w.z * xv.z + w.w * xv.w;
          }
        }
        p.rslab[(size_t)(((ks << 7) + b0 + bg) << 8) + n] = acc;
      }
      gbar(p.cnt, p.rel, ++gen);
    }
    // ---- gates: wih part (all 256 blocks) + whh part (bid<128) ----
    {
      const int jt = bid & 3, bt = (bid >> 2) & 3, ks = bid >> 4;  // 4,4,16
      const int b0 = bt * 32;
      const int nj = (jt << 6) + (tid & 63), bg = tid >> 6;  // 2 rows each
      float a00 = 0, a01 = 0, a02 = 0, a03 = 0;
      float a10 = 0, a11 = 0, a12 = 0, a13 = 0;
      const float* w0 = p.wih + (size_t)nj * 4096;
      const float* w1 = p.wih + (size_t)(nj + 256) * 4096;
      const float* w2 = p.wih + (size_t)(nj + 512) * 4096;
      const float* w3 = p.wih + (size_t)(nj + 768) * 4096;
#pragma unroll 1
      for (int sub = 0; sub < 2; ++sub) {
        const int kbase = (ks << 8) + (sub << 7);
        __syncthreads();
        {
          const int row = tid >> 5, col4 = tid & 31;
          *(float4*)&sm[(row << 7) + (col4 << 2)] =
              *(const float4*)(p.xm + (size_t)(b0 + row) * 4096 + kbase +
                               (col4 << 2));
        }
        __syncthreads();
        const float* x0 = &sm[(bg * 2) << 7];
        const float* x1 = &sm[(bg * 2 + 1) << 7];
        for (int k = 0; k < 128; k += 4) {
          float4 wa = *(const float4*)(w0 + kbase + k);
          float4 wb = *(const float4*)(w1 + kbase + k);
          float4 wc = *(const float4*)(w2 + kbase + k);
          float4 wd = *(const float4*)(w3 + kbase + k);
          float4 xa = *(const float4*)(x0 + k);
          float4 xb = *(const float4*)(x1 + k);
          a00 += wa.x * xa.x + wa.y * xa.y + wa.z * xa.z + wa.w * xa.w;
          a01 += wb.x * xa.x + wb.y * xa.y + wb.z * xa.z + wb.w * xa.w;
          a02 += wc.x * xa.x + wc.y * xa.y + wc.z * xa.z + wc.w * xa.w;
          a03 += wd.x * xa.x + wd.y * xa.y + wd.z * xa.z + wd.w * xa.w;
          a10 += wa.x * xb.x + wa.y * xb.y + wa.z * xb.z + wa.w * xb.w;
          a11 += wb.x * xb.x + wb.y * xb.y + wb.z * xb.z + wb.w * xb.w;
          a12 += wc.x * xb.x + wc.y * xb.y + wc.z * xb.z + wc.w * xb.w;
          a13 += wd.x * xb.x + wd.y * xb.y + wd.z * xb.z + wd.w * xb.w;
        }
      }
      {
        const size_t base0 =
            (size_t)ks * 131072 + (size_t)(b0 + bg * 2) * 1024 + nj;
        p.gslab[base0]       = a00;
        p.gslab[base0 + 256] = a01;
        p.gslab[base0 + 512] = a02;
        p.gslab[base0 + 768] = a03;
        const size_t base1 = base0 + 1024;
        p.gslab[base1]       = a10;
        p.gslab[base1 + 256] = a11;
        p.gslab[base1 + 512] = a12;
        p.gslab[base1 + 768] = a13;
      }
      __syncthreads();
      if (bid < 128) {  // whh part, hmfin2 fused into LDS fill
        const int nt2 = bid >> 2, bt2 = bid & 3;
        const int b02 = bt2 * 32;
        for (int i = tid; i < 8192; i += 1024) {
          const int bl = i >> 8, k = i & 255;
          const int b = b02 + bl;
          float acc = p.rb2[k];
#pragma unroll
          for (int ss = 0; ss < 8; ++ss)
            acc += p.rslab[(size_t)((ss * 128 + b) << 8) + k];
          sm[i] = 2.0f * sigf(acc) * p.hmB[(b << 8) + k];
        }
        __syncthreads();
        const int n2 = (nt2 << 5) + (tid & 31);
        const int bg2 = tid >> 5;  // 0..31
        const float* wrow = p.whh + (size_t)n2 * 256;
        const float* hr = &sm[bg2 << 8];
        float acc = 0.f;
        for (int k = 0; k < 256; k += 4) {
          float4 w  = *(const float4*)(wrow + k);
          float4 hv = *(const float4*)(hr + k);
          acc += w.x * hv.x + w.y * hv.y + w.z * hv.z + w.w * hv.w;
        }
        p.gslab[(size_t)16 * 131072 + (size_t)(b02 + bg2) * 1024 + n2] = acc;
      }
    }
    gbar(p.cnt, p.rel, ++gen);
  }
  // ---- FC ----
  if (bid < 128) {
    if (tid < 256) sm[tid] = p.h[(bid << 8) + tid];
    __syncthreads();
    if (tid < 5) {
      float acc = p.fcb[tid];
      const float* w = p.fcw + tid * 256;
      for (int k = 0; k < 256; ++k) acc += sm[k] * w[k];
      p.out[bid * 5 + tid] = acc;
    }
  }
}

// diagnostic: report ws_size (MiB) through the output if workspace too small
__global__ __launch_bounds__(256) void k_report(float* out, float v, int n) {
  int i = blockIdx.x * 256 + threadIdx.x;
  if (i < n) out[i] = v;
}

// ---------------------------------------------------------------------------
struct Net {
  const float *x;
  const float *c1a_w, *c1a_b, *g1a, *b1a, *m1a, *v1a;
  const float *c1b_w, *c1b_b, *g1b, *b1b, *m1b, *v1b;
  const float *c2a_w, *c2a_b, *g2a, *b2a, *m2a, *v2a;
  const float *c2b_w, *c2b_b, *g2b, *b2b, *m2b, *v2b;
  const float *qw[3], *qb[3], *rw[3], *rb[3];
  const float *wih, *whh, *bih, *bhh, *fcw, *fcb;
};

template <typename ZT>
static void run_all(const Net& p, ZT* z, u16* y1u, float* scr,
                    float* ps1, float* pss1, float* st1v,
                    float* ps2, float* pss2, float* st2v,
                    float* out, hipStream_t stream)
{
  float* xm    = scr;            // 524,288
  float* h     = scr + 524288;   // 32,768
  float* c     = scr + 557056;   // 32,768
  float* hmA   = scr + 589824;   // 32,768
  float* hmB   = scr + 622592;   // 32,768
  float* rslab = scr + 655360;   // 262,144
  float* gslab = scr + 917504;   // 2,228,224 (17 slabs of 131072)
  unsigned* cnt = (unsigned*)(scr + 3145728);  // barrier state (8 B)
  unsigned* rel = cnt + 1;

  k_conv1<<<dim3(128, 32), 256, 0, stream>>>(p.x, p.c1a_w, p.c1a_b, p.g1a,
      p.b1a, p.m1a, p.v1a, p.c1b_w, p.c1b_b, p.g1b, p.b1b, p.m1b, p.v1b,
      y1u, ps1, pss1);
  k_red<<<16, 256, 0, stream>>>(ps1, pss1, st1v, 32, 4096);
  k_simam_t<u16><<<4096, 256, 0, stream>>>(y1u, st1v, 4096);
  k_conv2<ZT><<<dim3(64, 128), 256, 0, stream>>>(y1u, p.c2a_w, p.c2a_b, p.g2a,
      p.b2a, p.m2a, p.v2a, p.c2b_w, p.c2b_b, p.g2b, p.b2b, p.m2b, p.v2b,
      z, ps2, pss2);
  k_red<<<32, 256, 0, stream>>>(ps2, pss2, st2v, 64, 8192);
  k_simam_t<ZT><<<8192, 256, 0, stream>>>(z, st2v, 8192);

  // barrier counters live in the y1u overlay region -> zero them only after
  // the CNN kernels (stream-ordered) are past their last y1u/scr use.
  hipMemsetAsync((void*)cnt, 0, 8, stream);

  LPar P;
  P.z = (const void*)z;
  P.qw0 = p.qw[0]; P.qb0 = p.qb[0]; P.rw0 = p.rw[0]; P.rb0 = p.rb[0];
  P.qw1 = p.qw[1]; P.qb1 = p.qb[1]; P.rw1 = p.rw[1]; P.rb1 = p.rb[1];
  P.qw2 = p.qw[2]; P.qb2 = p.qb[2]; P.rw2 = p.rw[2]; P.rb2 = p.rb[2];
  P.wih = p.wih; P.whh = p.whh; P.bih = p.bih; P.bhh = p.bhh;
  P.fcw = p.fcw; P.fcb = p.fcb;
  P.xm = xm; P.h = h; P.c = c; P.hmA = hmA; P.hmB = hmB;
  P.rslab = rslab; P.gslab = gslab;
  P.cnt = cnt; P.rel = rel; P.out = out;

  void* args[] = { (void*)&P };
  hipError_t e = hipLaunchCooperativeKernel(
      (const void*)k_lstm<ZT>, dim3(256), dim3(1024), args, 0, stream);
  if (e != hipSuccess) {
    (void)hipGetLastError();  // clear sticky error
    // 256 blocks x 1024 threads = exactly 1 block/CU on MI355X (256 CUs,
    // 32KB LDS, __launch_bounds__(1024,4) => <=128 VGPR): co-resident.
    k_lstm<ZT><<<dim3(256), dim3(1024), 0, stream>>>(P);
  }
}

extern "C" void kernel_launch(void* const* d_in, const int* in_sizes, int n_in,
                              void* d_out, int out_size, void* d_ws, size_t ws_size,
                              hipStream_t stream)
{
  (void)in_sizes; (void)n_in;
  Net p;
  p.x = (const float*)d_in[0];
  p.c1a_w = (const float*)d_in[1];  p.c1a_b = (const float*)d_in[2];
  p.g1a = (const float*)d_in[3];    p.b1a = (const float*)d_in[4];
  p.m1a = (const float*)d_in[5];    p.v1a = (const float*)d_in[6];
  p.c1b_w = (const float*)d_in[7];  p.c1b_b = (const float*)d_in[8];
  p.g1b = (const float*)d_in[9];    p.b1b = (const float*)d_in[10];
  p.m1b = (const float*)d_in[11];   p.v1b = (const float*)d_in[12];
  p.c2a_w = (const float*)d_in[13]; p.c2a_b = (const float*)d_in[14];
  p.g2a = (const float*)d_in[15];   p.b2a = (const float*)d_in[16];
  p.m2a = (const float*)d_in[17];   p.v2a = (const float*)d_in[18];
  p.c2b_w = (const float*)d_in[19]; p.c2b_b = (const float*)d_in[20];
  p.g2b = (const float*)d_in[21];   p.b2b = (const float*)d_in[22];
  p.m2b = (const float*)d_in[23];   p.v2b = (const float*)d_in[24];
  for (int i = 0; i < 3; ++i) {
    p.qw[i] = (const float*)d_in[25 + 4 * i];
    p.qb[i] = (const float*)d_in[26 + 4 * i];
    p.rw[i] = (const float*)d_in[27 + 4 * i];
    p.rb[i] = (const float*)d_in[28 + 4 * i];
  }
  p.wih = (const float*)d_in[37]; p.whh = (const float*)d_in[38];
  p.bih = (const float*)d_in[39]; p.bhh = (const float*)d_in[40];
  p.fcw = (const float*)d_in[41]; p.fcb = (const float*)d_in[42];
  float* out = (float*)d_out;
  char* base = (char*)d_ws;

  // z elems = 67,108,864 ; y1 elems = 33,554,432 ; stats block = 6,422,528 B
  const size_t ZB_F32 = 268435456, ZB_BF16 = 134217728, Y1B = 67108864;
  const size_t STATS = 1048576 * 2 + 65536 + 2097152 * 2 + 65536;
  const size_t HI_NEED = ZB_F32 + Y1B + STATS;   // ~326 MiB
  const size_t LO_NEED = ZB_BF16 + Y1B + STATS;  // ~198 MiB

  if (ws_size >= HI_NEED) {
    float* z = (float*)base;
    u16* y1u = (u16*)(base + ZB_F32);
    float* scr = (float*)(base + ZB_F32);  // overlays y1u after conv2 is done
    char* sb = base + ZB_F32 + Y1B;
    run_all<float>(p, z, y1u, scr,
                   (float*)sb, (float*)(sb + 1048576), (float*)(sb + 2097152),
                   (float*)(sb + 2162688), (float*)(sb + 4259840),
                   (float*)(sb + 6356992), out, stream);
  } else if (ws_size >= LO_NEED) {
    u16* z = (u16*)base;
    u16* y1u = (u16*)(base + ZB_BF16);
    float* scr = (float*)(base + ZB_BF16);  // overlays y1u after conv2 is done
    char* sb = base + ZB_BF16 + Y1B;
    run_all<u16>(p, z, y1u, scr,
                 (float*)sb, (float*)(sb + 1048576), (float*)(sb + 2097152),
                 (float*)(sb + 2162688), (float*)(sb + 4259840),
                 (float*)(sb + 6356992), out, stream);
  } else {
    k_report<<<3, 256, 0, stream>>>(out, (float)(ws_size >> 20), out_size);
  }
}

// Round 2
// 67064.417 us; speedup vs baseline: 1.4170x; 1.4170x over previous
//
#include <hip/hip_runtime.h>
#include <math.h>

// ---------------------------------------------------------------------------
// SimAM-CNN + Mogrifier-LSTM (Round 4): persistent LSTM, surgical coherence.
// B=128, T=128, D=64; CNN 1->32->32(3x3)->SimAM->(1x1)64->64(3x3)->SimAM;
// LSTM IN=4096,H=256, 128 steps, 3 mogrifier rounds; FC->5.
// Round-3 failure: barrier used ACQUIRE spins + __threadfence -> buffer_inv
// per poll iteration nuked the L2s (92us/barrier, 12.5GB HBM). Round-4:
//  - barrier = pure RELAXED agent atomics (2-level arrive, relaxed spin);
//    no cache-wide ops at all.
//  - cross-block data (xm,h,c,hm,gacc,gslab) accessed via RELAXED+AGENT
//    atomic ld/st (sc1, coherent at L3); weights/z stay normal L2-cached.
//  - rslab partial slabs replaced by fp32 device-scope atomicAdd into
//    ping-pong gaccA/gaccB (zeroed one phase ahead).
// ---------------------------------------------------------------------------

typedef unsigned short u16;

#define EPSBN 1e-5f

__device__ __forceinline__ float sigf(float x) { return 1.0f / (1.0f + expf(-x)); }

__device__ __forceinline__ float b2f(u16 u) {
  union { unsigned int i; float f; } v; v.i = ((unsigned int)u) << 16; return v.f;
}
__device__ __forceinline__ u16 f2b(float f) {
  union { float f; unsigned int i; } v; v.f = f;
  unsigned int r = v.i + 0x7FFFu + ((v.i >> 16) & 1u);
  return (u16)(r >> 16);
}

template <typename T> __device__ __forceinline__ float ld1(const T* p);
template <> __device__ __forceinline__ float ld1<float>(const float* p) { return *p; }
template <> __device__ __forceinline__ float ld1<u16>(const u16* p) { return b2f(*p); }
template <typename T> __device__ __forceinline__ void st1(T* p, float v);
template <> __device__ __forceinline__ void st1<float>(float* p, float v) { *p = v; }
template <> __device__ __forceinline__ void st1<u16>(u16* p, float v) { *p = f2b(v); }

// ---- device-coherent (agent-scope, relaxed) accessors: sc1, no cache ops ----
__device__ __forceinline__ float ldc(const float* p) {
  return __hip_atomic_load(p, __ATOMIC_RELAXED, __HIP_MEMORY_SCOPE_AGENT);
}
__device__ __forceinline__ void stc(float* p, float v) {
  __hip_atomic_store(p, v, __ATOMIC_RELAXED, __HIP_MEMORY_SCOPE_AGENT);
}
__device__ __forceinline__ float4 ldc4(const float* p) {
  union { unsigned long long u[2]; float4 f; } r;
  unsigned long long* q = (unsigned long long*)p;
  r.u[0] = __hip_atomic_load(q, __ATOMIC_RELAXED, __HIP_MEMORY_SCOPE_AGENT);
  r.u[1] = __hip_atomic_load(q + 1, __ATOMIC_RELAXED, __HIP_MEMORY_SCOPE_AGENT);
  return r.f;
}
__device__ __forceinline__ void addc(float* p, float v) {
  (void)__hip_atomic_fetch_add(p, v, __ATOMIC_RELAXED, __HIP_MEMORY_SCOPE_AGENT);
}

__device__ __forceinline__ float simam_elem(float xv, float s, float ss) {
  float mu = (s - xv) * (1.0f / 8191.0f);
  float var = (ss - xv * xv - 8191.0f * mu * mu) * (1.0f / 8190.0f);
  float einv = ((xv - mu) * (xv - mu) + 2.0f * var + 0.2f) / (4.0f * (var + 0.1f));
  return xv * sigf(einv);
}

// --------------------------- CNN stage 1 -----------------------------------
__global__ __launch_bounds__(256) void k_conv1(
    const float* __restrict__ x,
    const float* __restrict__ w1a, const float* __restrict__ b1a,
    const float* __restrict__ g1a, const float* __restrict__ bb1a,
    const float* __restrict__ m1a, const float* __restrict__ v1a,
    const float* __restrict__ w1b, const float* __restrict__ b1b,
    const float* __restrict__ g1b, const float* __restrict__ bb1b,
    const float* __restrict__ m1b, const float* __restrict__ v1b,
    u16* __restrict__ y1u, float* __restrict__ ps1, float* __restrict__ pss1)
{
  __shared__ float xs[6][66];
  __shared__ float a1[32][6][66];
  __shared__ float A1[32], T1[32], S2[32], T2[32];
  __shared__ float reds[4][32], redq[4][32];
  const int tid = threadIdx.x;
  const int b = blockIdx.x, t0 = blockIdx.y * 4;
  if (tid < 32) {
    float s = g1a[tid] * rsqrtf(v1a[tid] + EPSBN);
    A1[tid] = w1a[tid] * s;
    T1[tid] = (b1a[tid] - m1a[tid]) * s + bb1a[tid];
    float s2 = g1b[tid] * rsqrtf(v1b[tid] + EPSBN);
    S2[tid] = s2;
    T2[tid] = (b1b[tid] - m1b[tid]) * s2 + bb1b[tid];
  }
  for (int i = tid; i < 6 * 66; i += 256) {
    int r = i / 66, cc = i - r * 66;
    int t = t0 + r - 1, d = cc - 1;
    float v = 0.f;
    if (t >= 0 && t < 128 && d >= 0 && d < 64) v = x[(b * 128 + t) * 64 + d];
    xs[r][cc] = v;
  }
  __syncthreads();
  for (int i = tid; i < 32 * 6 * 66; i += 256) {
    int c = i / 396;
    int rr = i - c * 396;
    int r = rr / 66, cc = rr - r * 66;
    int t = t0 + r - 1, d = cc - 1;
    float v = 0.f;
    if (t >= 0 && t < 128 && d >= 0 && d < 64)
      v = fmaxf(xs[r][cc] * A1[c] + T1[c], 0.f);
    a1[c][r][cc] = v;
  }
  __syncthreads();
  const int d = tid & 63, tq = tid >> 6, lane = tid & 63;
  float acc[32];
#pragma unroll
  for (int i = 0; i < 32; ++i) acc[i] = 0.f;
#pragma unroll 1
  for (int c1 = 0; c1 < 32; ++c1) {
#pragma unroll
    for (int dt = 0; dt < 3; ++dt) {
      float av0 = a1[c1][tq + dt][d];
      float av1 = a1[c1][tq + dt][d + 1];
      float av2 = a1[c1][tq + dt][d + 2];
#pragma unroll
      for (int c2 = 0; c2 < 32; ++c2) {
        const float* wp = w1b + ((c2 * 32 + c1) * 3 + dt) * 3;  // uniform
        acc[c2] += av0 * wp[0] + av1 * wp[1] + av2 * wp[2];
      }
    }
  }
  const size_t ob = (size_t)b * 32 * 8192 + (size_t)(t0 + tq) * 64 + d;
#pragma unroll
  for (int c2 = 0; c2 < 32; ++c2) {
    float v = fmaxf(acc[c2] * S2[c2] + T2[c2], 0.f);
    y1u[ob + (size_t)c2 * 8192] = f2b(v);
    float s = v, q = v * v;
#pragma unroll
    for (int off = 32; off; off >>= 1) {
      s += __shfl_down(s, off);
      q += __shfl_down(q, off);
    }
    if (lane == 0) { reds[tq][c2] = s; redq[tq][c2] = q; }
  }
  __syncthreads();
  if (tid < 32) {
    float s = (reds[0][tid] + reds[1][tid]) + (reds[2][tid] + reds[3][tid]);
    float q = (redq[0][tid] + redq[1][tid]) + (redq[2][tid] + redq[3][tid]);
    ps1[(size_t)((b * 32 + tid) << 5) + blockIdx.y] = s;
    pss1[(size_t)((b * 32 + tid) << 5) + blockIdx.y] = q;
  }
}

__global__ __launch_bounds__(256) void k_red(
    const float* __restrict__ ps, const float* __restrict__ pss,
    float* __restrict__ stats, int npart, int nplanes)
{
  int p = blockIdx.x * 256 + threadIdx.x;
  if (p >= nplanes) return;
  float s = 0.f, q = 0.f;
  for (int j = 0; j < npart; ++j) {
    s += ps[(size_t)p * npart + j];
    q += pss[(size_t)p * npart + j];
  }
  stats[p] = s;
  stats[nplanes + p] = q;
}

template <typename T>
__global__ __launch_bounds__(256) void k_simam_t(
    T* __restrict__ buf, const float* __restrict__ stats, int nplanes)
{
  const int p = blockIdx.x, tid = threadIdx.x;
  T* base = buf + (size_t)p * 8192;
  const float s = stats[p], ss = stats[nplanes + p];
#pragma unroll 4
  for (int i = 0; i < 32; ++i) {
    int idx = tid + i * 256;
    float v = ld1(base + idx);
    st1(base + idx, simam_elem(v, s, ss));
  }
}

// --------------------------- CNN stage 2 -----------------------------------
template <typename ZT>
__global__ __launch_bounds__(256) void k_conv2(
    const u16* __restrict__ y1u,
    const float* __restrict__ w2a, const float* __restrict__ b2a,
    const float* __restrict__ g2a, const float* __restrict__ bb2a,
    const float* __restrict__ m2a, const float* __restrict__ v2a,
    const float* __restrict__ w2b, const float* __restrict__ b2b,
    const float* __restrict__ g2b, const float* __restrict__ bb2b,
    const float* __restrict__ m2b, const float* __restrict__ v2b,
    ZT* __restrict__ z, float* __restrict__ ps2, float* __restrict__ pss2)
{
  __shared__ float y1s[32][4][66];
  __shared__ float a2[64][4][66];
  __shared__ float sA2a[64], sT2a[64], sA2b[64], sT2b[64];
  const int tid = threadIdx.x;
  const int t0 = blockIdx.x * 2, b = blockIdx.y;
  if (tid < 64) {
    float sa = g2a[tid] * rsqrtf(v2a[tid] + EPSBN);
    sA2a[tid] = sa;
    sT2a[tid] = (b2a[tid] - m2a[tid]) * sa + bb2a[tid];
    float sb = g2b[tid] * rsqrtf(v2b[tid] + EPSBN);
    sA2b[tid] = sb;
    sT2b[tid] = (b2b[tid] - m2b[tid]) * sb + bb2b[tid];
  }
  for (int i = tid; i < 32 * 4 * 66; i += 256) {
    int c1 = i / 264;
    int rr = i - c1 * 264;
    int r = rr / 66, cc = rr - r * 66;
    int t = t0 + r - 1, dd = cc - 1;
    float v = 0.f;
    if (t >= 0 && t < 128 && dd >= 0 && dd < 64)
      v = b2f(y1u[(size_t)(b * 32 + c1) * 8192 + t * 64 + dd]);
    y1s[c1][r][cc] = v;
  }
  __syncthreads();
  const int lane = tid & 63;
  const int c2base = __builtin_amdgcn_readfirstlane((int)(tid >> 6)) * 16;
#pragma unroll 1
  for (int i = 0; i < 16; ++i) {
    const int c2 = c2base + i;
    const float* wp = w2a + c2 * 32;  // uniform
    const float scl = sA2a[c2], off = sT2a[c2];
#pragma unroll 1
    for (int r = 0; r < 4; ++r) {
      for (int cc = lane; cc < 66; cc += 64) {
        float acc = 0.f;
#pragma unroll
        for (int c1 = 0; c1 < 32; ++c1) acc += y1s[c1][r][cc] * wp[c1];
        int t = t0 + r - 1, dd = cc - 1;
        float val = 0.f;
        if (t >= 0 && t < 128 && dd >= 0 && dd < 64)
          val = fmaxf(acc * scl + off, 0.f);
        a2[c2][r][cc] = val;
      }
    }
  }
  __syncthreads();
  const int d = tid & 63;
  const int gq = __builtin_amdgcn_readfirstlane((int)(tid >> 6));
  float acc[16][2];
#pragma unroll
  for (int i = 0; i < 16; ++i) { acc[i][0] = 0.f; acc[i][1] = 0.f; }
#pragma unroll 1
  for (int c1 = 0; c1 < 64; ++c1) {
    float a00 = a2[c1][0][d], a01 = a2[c1][0][d + 1], a02 = a2[c1][0][d + 2];
    float a10 = a2[c1][1][d], a11 = a2[c1][1][d + 1], a12 = a2[c1][1][d + 2];
    float a20 = a2[c1][2][d], a21 = a2[c1][2][d + 1], a22 = a2[c1][2][d + 2];
    float a30 = a2[c1][3][d], a31 = a2[c1][3][d + 1], a32 = a2[c1][3][d + 2];
#pragma unroll
    for (int i = 0; i < 16; ++i) {
      const float* wp = w2b + (size_t)((gq * 16 + i) * 64 + c1) * 9;  // uniform
      float w0 = wp[0], w1 = wp[1], w2 = wp[2];
      float w3 = wp[3], w4 = wp[4], w5 = wp[5];
      float w6 = wp[6], w7 = wp[7], w8 = wp[8];
      acc[i][0] += a00 * w0 + a01 * w1 + a02 * w2 + a10 * w3 + a11 * w4 +
                   a12 * w5 + a20 * w6 + a21 * w7 + a22 * w8;
      acc[i][1] += a10 * w0 + a11 * w1 + a12 * w2 + a20 * w3 + a21 * w4 +
                   a22 * w5 + a30 * w6 + a31 * w7 + a32 * w8;
    }
  }
#pragma unroll
  for (int i = 0; i < 16; ++i) {
    int c2 = gq * 16 + i;
    float sc = sA2b[c2], tb = sT2b[c2];
    float v0 = fmaxf(acc[i][0] * sc + tb, 0.f);
    float v1 = fmaxf(acc[i][1] * sc + tb, 0.f);
    size_t ob = (size_t)(b * 64 + c2) * 8192 + (size_t)t0 * 64 + d;
    st1(z + ob, v0);
    st1(z + ob + 64, v1);
    float s = v0 + v1, q = v0 * v0 + v1 * v1;
#pragma unroll
    for (int off = 32; off; off >>= 1) {
      s += __shfl_down(s, off);
      q += __shfl_down(q, off);
    }
    if (lane == 0) {
      ps2[(size_t)((b * 64 + c2) << 6) + blockIdx.x] = s;
      pss2[(size_t)((b * 64 + c2) << 6) + blockIdx.x] = q;
    }
  }
}

// --------------------------- persistent LSTM -------------------------------
// Grid barrier, all-RELAXED agent atomics (no buffer_inv / buffer_wbl2):
// 2-level arrive: 8 spread cachelines x 32 blocks, then a root counter; last
// root arriver publishes rel=gen. Spinners poll with RELAXED loads + s_sleep.
// Data visibility: communicated buffers are accessed exclusively with
// agent-scope (sc1) ld/st, which are serviced at the device coherence point,
// and __syncthreads() (inside gbar, before arrive) drains vmcnt so all prior
// coherent stores have completed before the arrive-add is issued.
__device__ __forceinline__ void gbar(unsigned* bar, int bid, unsigned gen) {
  __syncthreads();
  if (threadIdx.x == 0) {
    unsigned* my = bar + ((bid & 7) << 5);   // 8 counters, 128B apart
    unsigned* root = bar + 256;
    unsigned* rel = bar + 288;
    unsigned prev = __hip_atomic_fetch_add(my, 1u, __ATOMIC_RELAXED,
                                           __HIP_MEMORY_SCOPE_AGENT);
    if (prev == gen * 32u - 1u) {
      unsigned p2 = __hip_atomic_fetch_add(root, 1u, __ATOMIC_RELAXED,
                                           __HIP_MEMORY_SCOPE_AGENT);
      if (p2 == gen * 8u - 1u)
        __hip_atomic_store(rel, gen, __ATOMIC_RELAXED,
                           __HIP_MEMORY_SCOPE_AGENT);
    }
    while (__hip_atomic_load(rel, __ATOMIC_RELAXED,
                             __HIP_MEMORY_SCOPE_AGENT) < gen) {
      __builtin_amdgcn_s_sleep(2);
    }
  }
  __syncthreads();
  asm volatile("" ::: "memory");
}

struct LPar {
  const void* z;
  const float* qw0; const float* qb0; const float* rw0; const float* rb0;
  const float* qw1; const float* qb1; const float* rw1; const float* rb1;
  const float* qw2; const float* qb2; const float* rw2; const float* rb2;
  const float* wih; const float* whh; const float* bih; const float* bhh;
  const float* fcw; const float* fcb;
  float* xm; float* h; float* c; float* hmA; float* hmB;
  float* gaccA; float* gaccB; float* gslab;
  unsigned* bar;
  float* out;
};

// 256 blocks x 1024 threads, 1 block/CU (4 waves/SIMD).
// Per step (8 grid barriers):
//   hfin | q0(zero A) | r0(add A) | q1(read A, zero B, hm0->hmA) | r1(add B) |
//   q2(read B, zero A, hm1->hmB) | r2(add A) |
//   gates: wih (all blocks) + whh (bid<128, hm2 = sig(A)*hmB fused)
template <typename ZT>
__global__ __launch_bounds__(1024, 4) void k_lstm(LPar p)
{
  __shared__ float sm[8192];  // 32 KB, reused per stage
  const int tid = threadIdx.x;
  const int bid = blockIdx.x;
  unsigned gen = 0;

  for (int t = 0; t <= 128; ++t) {
    // ---- hfin: h,c from gslab(t-1) ----
    if (bid < 32) {
      const int i = (bid << 10) + tid;
      const int b = i >> 8, k = i & 255;
      if (t == 0) {
        stc(p.h + i, 0.f); stc(p.c + i, 0.f);
      } else {
        float gi = p.bih[k]       + p.bhh[k];
        float gf = p.bih[k + 256] + p.bhh[k + 256];
        float gg = p.bih[k + 512] + p.bhh[k + 512];
        float go = p.bih[k + 768] + p.bhh[k + 768];
        const float* gs = p.gslab + b * 1024 + k;
#pragma unroll
        for (int s = 0; s < 17; ++s) {
          gi += ldc(gs + (size_t)s * 131072);
          gf += ldc(gs + (size_t)s * 131072 + 256);
          gg += ldc(gs + (size_t)s * 131072 + 512);
          go += ldc(gs + (size_t)s * 131072 + 768);
        }
        float cv = ldc(p.c + i);
        float cn = sigf(gf) * cv + sigf(gi) * tanhf(gg);
        stc(p.c + i, cn);
        stc(p.h + i, sigf(go) * tanhf(cn));
      }
    }
    gbar(p.bar, bid, ++gen);
    if (t == 128) break;

    const int qnt = bid & 63, qbt = bid >> 6;  // 64 n-tiles x 4 b-tiles
    const int qb0 = qbt * 32;

#pragma unroll 1
    for (int s = 0; s < 3; ++s) {
      // ---- q stage (s>0 fuses hmfin(s-1) into the LDS fill) ----
      {
        // zero the gacc buffer used by the UPCOMING r stage (32 blocks):
        // s=0 -> A (r0), s=1 -> B (r1), s=2 -> A (r2). Never the one read
        // this phase (q1 reads A, q2 reads B).
        if (bid < 32) {
          float* zb = (s == 1) ? p.gaccB : p.gaccA;
          stc(zb + (bid << 10) + tid, 0.f);
        }
        if (s == 0) {
          for (int i = tid; i < 8192; i += 1024)
            sm[i] = ldc(p.h + (qb0 << 8) + i);
        } else {
          const float* rbv = (s == 1) ? p.rb0 : p.rb1;
          const float* src = (s == 1) ? p.h : p.hmA;
          const float* ga  = (s == 1) ? p.gaccA : p.gaccB;
          for (int i = tid; i < 8192; i += 1024) {
            const int bl = i >> 8, k = i & 255;
            const int b = qb0 + bl;
            float acc = rbv[k] + ldc(ga + (b << 8) + k);
            sm[i] = 2.0f * sigf(acc) * ldc(src + (b << 8) + k);
          }
        }
        __syncthreads();
        if (s > 0 && qnt == 0) {  // 4 blocks store hm chunk for later stages
          float* dst = (s == 1) ? p.hmA : p.hmB;
          for (int i = tid; i < 8192; i += 1024)
            stc(dst + (qb0 << 8) + i, sm[i]);
        }
        const float* qW = (s == 0) ? p.qw0 : ((s == 1) ? p.qw1 : p.qw2);
        const float* qB = (s == 0) ? p.qb0 : ((s == 1) ? p.qb1 : p.qb2);
        const int n = (qnt << 6) + (tid & 63);
        const int bg = tid >> 6;  // 0..15, rows bg*2, bg*2+1
        const float* wrow = qW + (size_t)n * 256;
        const float* h0 = &sm[(bg * 2) << 8];
        const float* h1 = &sm[(bg * 2 + 1) << 8];
        float acc0 = 0.f, acc1 = 0.f;
        for (int k = 0; k < 256; k += 4) {
          float4 w  = *(const float4*)(wrow + k);
          float4 a4 = *(const float4*)(h0 + k);
          float4 b4 = *(const float4*)(h1 + k);
          acc0 += w.x * a4.x + w.y * a4.y + w.z * a4.z + w.w * a4.w;
          acc1 += w.x * b4.x + w.y * b4.y + w.z * b4.z + w.w * b4.w;
        }
        const float bias = qB[n];
        const int b_0 = qb0 + bg * 2, b_1 = b_0 + 1;
        float xv0, xv1;
        if (s == 0) {
          const ZT* zz = (const ZT*)p.z;
          xv0 = ld1(zz + (size_t)b_0 * 524288 + t * 4096 + n);
          xv1 = ld1(zz + (size_t)b_1 * 524288 + t * 4096 + n);
        } else {
          xv0 = ldc(p.xm + (size_t)b_0 * 4096 + n);
          xv1 = ldc(p.xm + (size_t)b_1 * 4096 + n);
        }
        stc(p.xm + (size_t)b_0 * 4096 + n, 2.0f * sigf(acc0 + bias) * xv0);
        stc(p.xm + (size_t)b_1 * 4096 + n, 2.0f * sigf(acc1 + bias) * xv1);
      }
      gbar(p.bar, bid, ++gen);
      // ---- r stage: atomicAdd K-split partials into gacc ----
      {
        const float* rW = (s == 0) ? p.rw0 : ((s == 1) ? p.rw1 : p.rw2);
        float* ga = (s == 1) ? p.gaccB : p.gaccA;
        const int nt = bid & 7, bt = (bid >> 3) & 3, ks = bid >> 5;
        const int n = (nt << 5) + (tid & 31);
        const int b0 = bt * 32, bg = tid >> 5;  // 0..31, one b-row each
        const float* wrow = rW + (size_t)n * 4096;
        float acc = 0.f;
#pragma unroll 1
        for (int sub = 0; sub < 4; ++sub) {
          const int kbase = (ks << 9) + (sub << 7);
          __syncthreads();
          {
            const int row = tid >> 5, col4 = tid & 31;  // 1024 float4 = tile
            *(float4*)&sm[(row << 7) + (col4 << 2)] =
                ldc4(p.xm + (size_t)(b0 + row) * 4096 + kbase + (col4 << 2));
          }
          __syncthreads();
          const float* xr = &sm[bg << 7];
          for (int k = 0; k < 128; k += 4) {
            float4 w  = *(const float4*)(wrow + kbase + k);
            float4 xv = *(const float4*)(xr + k);
            acc += w.x * xv.x + w.y * xv.y + w.z * xv.z + w.w * xv.w;
          }
        }
        addc(ga + ((b0 + bg) << 8) + n, acc);
      }
      gbar(p.bar, bid, ++gen);
    }
    // ---- gates: wih part (all 256 blocks) + whh part (bid<128) ----
    {
      const int jt = bid & 3, bt = (bid >> 2) & 3, ks = bid >> 4;  // 4,4,16
      const int b0 = bt * 32;
      const int nj = (jt << 6) + (tid & 63), bg = tid >> 6;  // 2 rows each
      float a00 = 0, a01 = 0, a02 = 0, a03 = 0;
      float a10 = 0, a11 = 0, a12 = 0, a13 = 0;
      const float* w0 = p.wih + (size_t)nj * 4096;
      const float* w1 = p.wih + (size_t)(nj + 256) * 4096;
      const float* w2 = p.wih + (size_t)(nj + 512) * 4096;
      const float* w3 = p.wih + (size_t)(nj + 768) * 4096;
#pragma unroll 1
      for (int sub = 0; sub < 2; ++sub) {
        const int kbase = (ks << 8) + (sub << 7);
        __syncthreads();
        {
          const int row = tid >> 5, col4 = tid & 31;
          *(float4*)&sm[(row << 7) + (col4 << 2)] =
              ldc4(p.xm + (size_t)(b0 + row) * 4096 + kbase + (col4 << 2));
        }
        __syncthreads();
        const float* x0 = &sm[(bg * 2) << 7];
        const float* x1 = &sm[(bg * 2 + 1) << 7];
        for (int k = 0; k < 128; k += 4) {
          float4 wa = *(const float4*)(w0 + kbase + k);
          float4 wb = *(const float4*)(w1 + kbase + k);
          float4 wc = *(const float4*)(w2 + kbase + k);
          float4 wd = *(const float4*)(w3 + kbase + k);
          float4 xa = *(const float4*)(x0 + k);
          float4 xb = *(const float4*)(x1 + k);
          a00 += wa.x * xa.x + wa.y * xa.y + wa.z * xa.z + wa.w * xa.w;
          a01 += wb.x * xa.x + wb.y * xa.y + wb.z * xa.z + wb.w * xa.w;
          a02 += wc.x * xa.x + wc.y * xa.y + wc.z * xa.z + wc.w * xa.w;
          a03 += wd.x * xa.x + wd.y * xa.y + wd.z * xa.z + wd.w * xa.w;
          a10 += wa.x * xb.x + wa.y * xb.y + wa.z * xb.z + wa.w * xb.w;
          a11 += wb.x * xb.x + wb.y * xb.y + wb.z * xb.z + wb.w * xb.w;
          a12 += wc.x * xb.x + wc.y * xb.y + wc.z * xb.z + wc.w * xb.w;
          a13 += wd.x * xb.x + wd.y * xb.y + wd.z * xb.z + wd.w * xb.w;
        }
      }
      {
        float* base0 =
            p.gslab + (size_t)ks * 131072 + (size_t)(b0 + bg * 2) * 1024 + nj;
        stc(base0,       a00);
        stc(base0 + 256, a01);
        stc(base0 + 512, a02);
        stc(base0 + 768, a03);
        float* base1 = base0 + 1024;
        stc(base1,       a10);
        stc(base1 + 256, a11);
        stc(base1 + 512, a12);
        stc(base1 + 768, a13);
      }
      __syncthreads();
      if (bid < 128) {  // whh part, hmfin2 = 2*sig(gaccA+rb2)*hmB fused
        const int nt2 = bid >> 2, bt2 = bid & 3;
        const int b02 = bt2 * 32;
        for (int i = tid; i < 8192; i += 1024) {
          const int bl = i >> 8, k = i & 255;
          const int b = b02 + bl;
          float acc = p.rb2[k] + ldc(p.gaccA + (b << 8) + k);
          sm[i] = 2.0f * sigf(acc) * ldc(p.hmB + (b << 8) + k);
        }
        __syncthreads();
        const int n2 = (nt2 << 5) + (tid & 31);
        const int bg2 = tid >> 5;  // 0..31
        const float* wrow = p.whh + (size_t)n2 * 256;
        const float* hr = &sm[bg2 << 8];
        float acc = 0.f;
        for (int k = 0; k < 256; k += 4) {
          float4 w  = *(const float4*)(wrow + k);
          float4 hv = *(const float4*)(hr + k);
          acc += w.x * hv.x + w.y * hv.y + w.z * hv.z + w.w * hv.w;
        }
        stc(p.gslab + (size_t)16 * 131072 + (size_t)(b02 + bg2) * 1024 + n2,
            acc);
      }
    }
    gbar(p.bar, bid, ++gen);
  }
  // ---- FC ----
  if (bid < 128) {
    if (tid < 256) sm[tid] = ldc(p.h + (bid << 8) + tid);
    __syncthreads();
    if (tid < 5) {
      float acc = p.fcb[tid];
      const float* w = p.fcw + tid * 256;
      for (int k = 0; k < 256; ++k) acc += sm[k] * w[k];
      p.out[bid * 5 + tid] = acc;
    }
  }
}

// diagnostic: report ws_size (MiB) through the output if workspace too small
__global__ __launch_bounds__(256) void k_report(float* out, float v, int n) {
  int i = blockIdx.x * 256 + threadIdx.x;
  if (i < n) out[i] = v;
}

// ---------------------------------------------------------------------------
struct Net {
  const float *x;
  const float *c1a_w, *c1a_b, *g1a, *b1a, *m1a, *v1a;
  const float *c1b_w, *c1b_b, *g1b, *b1b, *m1b, *v1b;
  const float *c2a_w, *c2a_b, *g2a, *b2a, *m2a, *v2a;
  const float *c2b_w, *c2b_b, *g2b, *b2b, *m2b, *v2b;
  const float *qw[3], *qb[3], *rw[3], *rb[3];
  const float *wih, *whh, *bih, *bhh, *fcw, *fcb;
};

template <typename ZT>
static void run_all(const Net& p, ZT* z, u16* y1u, float* scr,
                    float* ps1, float* pss1, float* st1v,
                    float* ps2, float* pss2, float* st2v,
                    float* out, hipStream_t stream)
{
  float* xm    = scr;            // 524,288
  float* h     = scr + 524288;   // 32,768
  float* c     = scr + 557056;   // 32,768
  float* hmA   = scr + 589824;   // 32,768
  float* hmB   = scr + 622592;   // 32,768
  float* gaccA = scr + 655360;   // 32,768
  float* gaccB = scr + 688128;   // 32,768
  float* gslab = scr + 720896;   // 2,228,224 (17 slabs of 131072)
  unsigned* bar = (unsigned*)(scr + 2949120);  // 512 u32 barrier state

  k_conv1<<<dim3(128, 32), 256, 0, stream>>>(p.x, p.c1a_w, p.c1a_b, p.g1a,
      p.b1a, p.m1a, p.v1a, p.c1b_w, p.c1b_b, p.g1b, p.b1b, p.m1b, p.v1b,
      y1u, ps1, pss1);
  k_red<<<16, 256, 0, stream>>>(ps1, pss1, st1v, 32, 4096);
  k_simam_t<u16><<<4096, 256, 0, stream>>>(y1u, st1v, 4096);
  k_conv2<ZT><<<dim3(64, 128), 256, 0, stream>>>(y1u, p.c2a_w, p.c2a_b, p.g2a,
      p.b2a, p.m2a, p.v2a, p.c2b_w, p.c2b_b, p.g2b, p.b2b, p.m2b, p.v2b,
      z, ps2, pss2);
  k_red<<<32, 256, 0, stream>>>(ps2, pss2, st2v, 64, 8192);
  k_simam_t<ZT><<<8192, 256, 0, stream>>>(z, st2v, 8192);

  // barrier state lives in the y1u overlay region -> zero it only after the
  // CNN kernels (stream-ordered) are past their last y1u/scr use.
  hipMemsetAsync((void*)bar, 0, 2048, stream);

  LPar P;
  P.z = (const void*)z;
  P.qw0 = p.qw[0]; P.qb0 = p.qb[0]; P.rw0 = p.rw[0]; P.rb0 = p.rb[0];
  P.qw1 = p.qw[1]; P.qb1 = p.qb[1]; P.rw1 = p.rw[1]; P.rb1 = p.rb[1];
  P.qw2 = p.qw[2]; P.qb2 = p.qb[2]; P.rw2 = p.rw[2]; P.rb2 = p.rb[2];
  P.wih = p.wih; P.whh = p.whh; P.bih = p.bih; P.bhh = p.bhh;
  P.fcw = p.fcw; P.fcb = p.fcb;
  P.xm = xm; P.h = h; P.c = c; P.hmA = hmA; P.hmB = hmB;
  P.gaccA = gaccA; P.gaccB = gaccB; P.gslab = gslab;
  P.bar = bar; P.out = out;

  void* args[] = { (void*)&P };
  hipError_t e = hipLaunchCooperativeKernel(
      (const void*)k_lstm<ZT>, dim3(256), dim3(1024), args, 0, stream);
  if (e != hipSuccess) {
    (void)hipGetLastError();  // clear sticky error
    // 256 blocks x 1024 threads = exactly 1 block/CU on MI355X (256 CUs,
    // 32KB LDS, __launch_bounds__(1024,4) => <=128 VGPR): co-resident.
    k_lstm<ZT><<<dim3(256), dim3(1024), 0, stream>>>(P);
  }
}

extern "C" void kernel_launch(void* const* d_in, const int* in_sizes, int n_in,
                              void* d_out, int out_size, void* d_ws, size_t ws_size,
                              hipStream_t stream)
{
  (void)in_sizes; (void)n_in;
  Net p;
  p.x = (const float*)d_in[0];
  p.c1a_w = (const float*)d_in[1];  p.c1a_b = (const float*)d_in[2];
  p.g1a = (const float*)d_in[3];    p.b1a = (const float*)d_in[4];
  p.m1a = (const float*)d_in[5];    p.v1a = (const float*)d_in[6];
  p.c1b_w = (const float*)d_in[7];  p.c1b_b = (const float*)d_in[8];
  p.g1b = (const float*)d_in[9];    p.b1b = (const float*)d_in[10];
  p.m1b = (const float*)d_in[11];   p.v1b = (const float*)d_in[12];
  p.c2a_w = (const float*)d_in[13]; p.c2a_b = (const float*)d_in[14];
  p.g2a = (const float*)d_in[15];   p.b2a = (const float*)d_in[16];
  p.m2a = (const float*)d_in[17];   p.v2a = (const float*)d_in[18];
  p.c2b_w = (const float*)d_in[19]; p.c2b_b = (const float*)d_in[20];
  p.g2b = (const float*)d_in[21];   p.b2b = (const float*)d_in[22];
  p.m2b = (const float*)d_in[23];   p.v2b = (const float*)d_in[24];
  for (int i = 0; i < 3; ++i) {
    p.qw[i] = (const float*)d_in[25 + 4 * i];
    p.qb[i] = (const float*)d_in[26 + 4 * i];
    p.rw[i] = (const float*)d_in[27 + 4 * i];
    p.rb[i] = (const float*)d_in[28 + 4 * i];
  }
  p.wih = (const float*)d_in[37]; p.whh = (const float*)d_in[38];
  p.bih = (const float*)d_in[39]; p.bhh = (const float*)d_in[40];
  p.fcw = (const float*)d_in[41]; p.fcb = (const float*)d_in[42];
  float* out = (float*)d_out;
  char* base = (char*)d_ws;

  // z elems = 67,108,864 ; y1 elems = 33,554,432 ; stats block = 6,422,528 B
  const size_t ZB_F32 = 268435456, ZB_BF16 = 134217728, Y1B = 67108864;
  const size_t STATS = 1048576 * 2 + 65536 + 2097152 * 2 + 65536;
  const size_t HI_NEED = ZB_F32 + Y1B + STATS;   // ~326 MiB
  const size_t LO_NEED = ZB_BF16 + Y1B + STATS;  // ~198 MiB

  if (ws_size >= HI_NEED) {
    float* z = (float*)base;
    u16* y1u = (u16*)(base + ZB_F32);
    float* scr = (float*)(base + ZB_F32);  // overlays y1u after conv2 is done
    char* sb = base + ZB_F32 + Y1B;
    run_all<float>(p, z, y1u, scr,
                   (float*)sb, (float*)(sb + 1048576), (float*)(sb + 2097152),
                   (float*)(sb + 2162688), (float*)(sb + 4259840),
                   (float*)(sb + 6356992), out, stream);
  } else if (ws_size >= LO_NEED) {
    u16* z = (u16*)base;
    u16* y1u = (u16*)(base + ZB_BF16);
    float* scr = (float*)(base + ZB_BF16);  // overlays y1u after conv2 is done
    char* sb = base + ZB_BF16 + Y1B;
    run_all<u16>(p, z, y1u, scr,
                 (float*)sb, (float*)(sb + 1048576), (float*)(sb + 2097152),
                 (float*)(sb + 2162688), (float*)(sb + 4259840),
                 (float*)(sb + 6356992), out, stream);
  } else {
    k_report<<<3, 256, 0, stream>>>(out, (float)(ws_size >> 20), out_size);
  }
}

// Round 3
// 41336.121 us; speedup vs baseline: 2.2990x; 1.6224x over previous
//
#include <hip/hip_runtime.h>
#include <math.h>

// ---------------------------------------------------------------------------
// SimAM-CNN + Mogrifier-LSTM (Round 5): XCD-partitioned persistent LSTM.
// The LSTM recurrence is batch-parallel: rows [g*16,(g+1)*16) are owned by
// XCD g (8 XCDs x 32 CUs, discovered via s_getreg(HW_REG_XCC_ID); 100KB LDS
// forces 1 block/CU so each XCD has exactly 32 blocks). Cross-block data
// (xm/hm/gates) lives in that XCD's L2: plain write-through stores + plain
// loads + buffer_inv (per-CU L1 invalidate) at each intra-XCD barrier, which
// uses L2-executed workgroup-scope atomics. No agent-scope data traffic.
// h,c kept redundantly in per-block LDS (zero communication).
// Fallback (rendezvous detects bad grouping): same body with sc1 accessors +
// agent barriers (round-4 semantics, slow but correct).
// ---------------------------------------------------------------------------

typedef unsigned short u16;

#define EPSBN 1e-5f

__device__ __forceinline__ float sigf(float x) { return 1.0f / (1.0f + expf(-x)); }

__device__ __forceinline__ float b2f(u16 u) {
  union { unsigned int i; float f; } v; v.i = ((unsigned int)u) << 16; return v.f;
}
__device__ __forceinline__ u16 f2b(float f) {
  union { float f; unsigned int i; } v; v.f = f;
  unsigned int r = v.i + 0x7FFFu + ((v.i >> 16) & 1u);
  return (u16)(r >> 16);
}

template <typename T> __device__ __forceinline__ float ld1(const T* p);
template <> __device__ __forceinline__ float ld1<float>(const float* p) { return *p; }
template <> __device__ __forceinline__ float ld1<u16>(const u16* p) { return b2f(*p); }
template <typename T> __device__ __forceinline__ void st1(T* p, float v);
template <> __device__ __forceinline__ void st1<float>(float* p, float v) { *p = v; }
template <> __device__ __forceinline__ void st1<u16>(u16* p, float v) { *p = f2b(v); }

// ---- access policies -------------------------------------------------------
// MODE 0 (fast): plain loads/stores; coherence = same-XCD L2 (write-through
//   L1, stores drained by __syncthreads before barrier arrive; readers get a
//   buffer_inv L1 invalidate at the barrier).
// MODE 1 (generic): sc1 agent-scope atomics (device coherence point).
template <int MODE> struct Acc;
template <> struct Acc<0> {
  static __device__ __forceinline__ float ld(const float* p) { return *p; }
  static __device__ __forceinline__ float4 ld4(const float* p) {
    return *(const float4*)p;
  }
  static __device__ __forceinline__ void st(float* p, float v) { *p = v; }
};
template <> struct Acc<1> {
  static __device__ __forceinline__ float ld(const float* p) {
    return __hip_atomic_load(p, __ATOMIC_RELAXED, __HIP_MEMORY_SCOPE_AGENT);
  }
  static __device__ __forceinline__ float4 ld4(const float* p) {
    union { unsigned long long u[2]; float4 f; } r;
    const unsigned long long* q = (const unsigned long long*)p;
    r.u[0] = __hip_atomic_load(q, __ATOMIC_RELAXED, __HIP_MEMORY_SCOPE_AGENT);
    r.u[1] = __hip_atomic_load(q + 1, __ATOMIC_RELAXED, __HIP_MEMORY_SCOPE_AGENT);
    return r.f;
  }
  static __device__ __forceinline__ void st(float* p, float v) {
    __hip_atomic_store(p, v, __ATOMIC_RELAXED, __HIP_MEMORY_SCOPE_AGENT);
  }
};

__device__ __forceinline__ float simam_elem(float xv, float s, float ss) {
  float mu = (s - xv) * (1.0f / 8191.0f);
  float var = (ss - xv * xv - 8191.0f * mu * mu) * (1.0f / 8190.0f);
  float einv = ((xv - mu) * (xv - mu) + 2.0f * var + 0.2f) / (4.0f * (var + 0.1f));
  return xv * sigf(einv);
}

// --------------------------- CNN stage 1 -----------------------------------
__global__ __launch_bounds__(256) void k_conv1(
    const float* __restrict__ x,
    const float* __restrict__ w1a, const float* __restrict__ b1a,
    const float* __restrict__ g1a, const float* __restrict__ bb1a,
    const float* __restrict__ m1a, const float* __restrict__ v1a,
    const float* __restrict__ w1b, const float* __restrict__ b1b,
    const float* __restrict__ g1b, const float* __restrict__ bb1b,
    const float* __restrict__ m1b, const float* __restrict__ v1b,
    u16* __restrict__ y1u, float* __restrict__ ps1, float* __restrict__ pss1)
{
  __shared__ float xs[6][66];
  __shared__ float a1[32][6][66];
  __shared__ float A1[32], T1[32], S2[32], T2[32];
  __shared__ float reds[4][32], redq[4][32];
  const int tid = threadIdx.x;
  const int b = blockIdx.x, t0 = blockIdx.y * 4;
  if (tid < 32) {
    float s = g1a[tid] * rsqrtf(v1a[tid] + EPSBN);
    A1[tid] = w1a[tid] * s;
    T1[tid] = (b1a[tid] - m1a[tid]) * s + bb1a[tid];
    float s2 = g1b[tid] * rsqrtf(v1b[tid] + EPSBN);
    S2[tid] = s2;
    T2[tid] = (b1b[tid] - m1b[tid]) * s2 + bb1b[tid];
  }
  for (int i = tid; i < 6 * 66; i += 256) {
    int r = i / 66, cc = i - r * 66;
    int t = t0 + r - 1, d = cc - 1;
    float v = 0.f;
    if (t >= 0 && t < 128 && d >= 0 && d < 64) v = x[(b * 128 + t) * 64 + d];
    xs[r][cc] = v;
  }
  __syncthreads();
  for (int i = tid; i < 32 * 6 * 66; i += 256) {
    int c = i / 396;
    int rr = i - c * 396;
    int r = rr / 66, cc = rr - r * 66;
    int t = t0 + r - 1, d = cc - 1;
    float v = 0.f;
    if (t >= 0 && t < 128 && d >= 0 && d < 64)
      v = fmaxf(xs[r][cc] * A1[c] + T1[c], 0.f);
    a1[c][r][cc] = v;
  }
  __syncthreads();
  const int d = tid & 63, tq = tid >> 6, lane = tid & 63;
  float acc[32];
#pragma unroll
  for (int i = 0; i < 32; ++i) acc[i] = 0.f;
#pragma unroll 1
  for (int c1 = 0; c1 < 32; ++c1) {
#pragma unroll
    for (int dt = 0; dt < 3; ++dt) {
      float av0 = a1[c1][tq + dt][d];
      float av1 = a1[c1][tq + dt][d + 1];
      float av2 = a1[c1][tq + dt][d + 2];
#pragma unroll
      for (int c2 = 0; c2 < 32; ++c2) {
        const float* wp = w1b + ((c2 * 32 + c1) * 3 + dt) * 3;  // uniform
        acc[c2] += av0 * wp[0] + av1 * wp[1] + av2 * wp[2];
      }
    }
  }
  const size_t ob = (size_t)b * 32 * 8192 + (size_t)(t0 + tq) * 64 + d;
#pragma unroll
  for (int c2 = 0; c2 < 32; ++c2) {
    float v = fmaxf(acc[c2] * S2[c2] + T2[c2], 0.f);
    y1u[ob + (size_t)c2 * 8192] = f2b(v);
    float s = v, q = v * v;
#pragma unroll
    for (int off = 32; off; off >>= 1) {
      s += __shfl_down(s, off);
      q += __shfl_down(q, off);
    }
    if (lane == 0) { reds[tq][c2] = s; redq[tq][c2] = q; }
  }
  __syncthreads();
  if (tid < 32) {
    float s = (reds[0][tid] + reds[1][tid]) + (reds[2][tid] + reds[3][tid]);
    float q = (redq[0][tid] + redq[1][tid]) + (redq[2][tid] + redq[3][tid]);
    ps1[(size_t)((b * 32 + tid) << 5) + blockIdx.y] = s;
    pss1[(size_t)((b * 32 + tid) << 5) + blockIdx.y] = q;
  }
}

__global__ __launch_bounds__(256) void k_red(
    const float* __restrict__ ps, const float* __restrict__ pss,
    float* __restrict__ stats, int npart, int nplanes)
{
  int p = blockIdx.x * 256 + threadIdx.x;
  if (p >= nplanes) return;
  float s = 0.f, q = 0.f;
  for (int j = 0; j < npart; ++j) {
    s += ps[(size_t)p * npart + j];
    q += pss[(size_t)p * npart + j];
  }
  stats[p] = s;
  stats[nplanes + p] = q;
}

template <typename T>
__global__ __launch_bounds__(256) void k_simam_t(
    T* __restrict__ buf, const float* __restrict__ stats, int nplanes)
{
  const int p = blockIdx.x, tid = threadIdx.x;
  T* base = buf + (size_t)p * 8192;
  const float s = stats[p], ss = stats[nplanes + p];
#pragma unroll 4
  for (int i = 0; i < 32; ++i) {
    int idx = tid + i * 256;
    float v = ld1(base + idx);
    st1(base + idx, simam_elem(v, s, ss));
  }
}

// --------------------------- CNN stage 2 -----------------------------------
template <typename ZT>
__global__ __launch_bounds__(256) void k_conv2(
    const u16* __restrict__ y1u,
    const float* __restrict__ w2a, const float* __restrict__ b2a,
    const float* __restrict__ g2a, const float* __restrict__ bb2a,
    const float* __restrict__ m2a, const float* __restrict__ v2a,
    const float* __restrict__ w2b, const float* __restrict__ b2b,
    const float* __restrict__ g2b, const float* __restrict__ bb2b,
    const float* __restrict__ m2b, const float* __restrict__ v2b,
    ZT* __restrict__ z, float* __restrict__ ps2, float* __restrict__ pss2)
{
  __shared__ float y1s[32][4][66];
  __shared__ float a2[64][4][66];
  __shared__ float sA2a[64], sT2a[64], sA2b[64], sT2b[64];
  const int tid = threadIdx.x;
  const int t0 = blockIdx.x * 2, b = blockIdx.y;
  if (tid < 64) {
    float sa = g2a[tid] * rsqrtf(v2a[tid] + EPSBN);
    sA2a[tid] = sa;
    sT2a[tid] = (b2a[tid] - m2a[tid]) * sa + bb2a[tid];
    float sb = g2b[tid] * rsqrtf(v2b[tid] + EPSBN);
    sA2b[tid] = sb;
    sT2b[tid] = (b2b[tid] - m2b[tid]) * sb + bb2b[tid];
  }
  for (int i = tid; i < 32 * 4 * 66; i += 256) {
    int c1 = i / 264;
    int rr = i - c1 * 264;
    int r = rr / 66, cc = rr - r * 66;
    int t = t0 + r - 1, dd = cc - 1;
    float v = 0.f;
    if (t >= 0 && t < 128 && dd >= 0 && dd < 64)
      v = b2f(y1u[(size_t)(b * 32 + c1) * 8192 + t * 64 + dd]);
    y1s[c1][r][cc] = v;
  }
  __syncthreads();
  const int lane = tid & 63;
  const int c2base = __builtin_amdgcn_readfirstlane((int)(tid >> 6)) * 16;
#pragma unroll 1
  for (int i = 0; i < 16; ++i) {
    const int c2 = c2base + i;
    const float* wp = w2a + c2 * 32;  // uniform
    const float scl = sA2a[c2], off = sT2a[c2];
#pragma unroll 1
    for (int r = 0; r < 4; ++r) {
      for (int cc = lane; cc < 66; cc += 64) {
        float acc = 0.f;
#pragma unroll
        for (int c1 = 0; c1 < 32; ++c1) acc += y1s[c1][r][cc] * wp[c1];
        int t = t0 + r - 1, dd = cc - 1;
        float val = 0.f;
        if (t >= 0 && t < 128 && dd >= 0 && dd < 64)
          val = fmaxf(acc * scl + off, 0.f);
        a2[c2][r][cc] = val;
      }
    }
  }
  __syncthreads();
  const int d = tid & 63;
  const int gq = __builtin_amdgcn_readfirstlane((int)(tid >> 6));
  float acc[16][2];
#pragma unroll
  for (int i = 0; i < 16; ++i) { acc[i][0] = 0.f; acc[i][1] = 0.f; }
#pragma unroll 1
  for (int c1 = 0; c1 < 64; ++c1) {
    float a00 = a2[c1][0][d], a01 = a2[c1][0][d + 1], a02 = a2[c1][0][d + 2];
    float a10 = a2[c1][1][d], a11 = a2[c1][1][d + 1], a12 = a2[c1][1][d + 2];
    float a20 = a2[c1][2][d], a21 = a2[c1][2][d + 1], a22 = a2[c1][2][d + 2];
    float a30 = a2[c1][3][d], a31 = a2[c1][3][d + 1], a32 = a2[c1][3][d + 2];
#pragma unroll
    for (int i = 0; i < 16; ++i) {
      const float* wp = w2b + (size_t)((gq * 16 + i) * 64 + c1) * 9;  // uniform
      float w0 = wp[0], w1 = wp[1], w2 = wp[2];
      float w3 = wp[3], w4 = wp[4], w5 = wp[5];
      float w6 = wp[6], w7 = wp[7], w8 = wp[8];
      acc[i][0] += a00 * w0 + a01 * w1 + a02 * w2 + a10 * w3 + a11 * w4 +
                   a12 * w5 + a20 * w6 + a21 * w7 + a22 * w8;
      acc[i][1] += a10 * w0 + a11 * w1 + a12 * w2 + a20 * w3 + a21 * w4 +
                   a22 * w5 + a30 * w6 + a31 * w7 + a32 * w8;
    }
  }
#pragma unroll
  for (int i = 0; i < 16; ++i) {
    int c2 = gq * 16 + i;
    float sc = sA2b[c2], tb = sT2b[c2];
    float v0 = fmaxf(acc[i][0] * sc + tb, 0.f);
    float v1 = fmaxf(acc[i][1] * sc + tb, 0.f);
    size_t ob = (size_t)(b * 64 + c2) * 8192 + (size_t)t0 * 64 + d;
    st1(z + ob, v0);
    st1(z + ob + 64, v1);
    float s = v0 + v1, q = v0 * v0 + v1 * v1;
#pragma unroll
    for (int off = 32; off; off >>= 1) {
      s += __shfl_down(s, off);
      q += __shfl_down(q, off);
    }
    if (lane == 0) {
      ps2[(size_t)((b * 64 + c2) << 6) + blockIdx.x] = s;
      pss2[(size_t)((b * 64 + c2) << 6) + blockIdx.x] = q;
    }
  }
}

// --------------------------- persistent LSTM -------------------------------
struct LPar {
  const void* z;
  const float *qw0, *qb0, *rw0, *rb0;
  const float *qw1, *qb1, *rw1, *rb1;
  const float *qw2, *qb2, *rw2, *rb2;
  const float *wih, *whh, *bih, *bhh, *fcw, *fcb;
  float* grp;     // 8 groups x 131072 floats
  unsigned* bar;  // barrier / rendezvous state
  float* out;
};

// bar layout (u32 indices): fast group bars g*64 (cnt), g*64+32 (rel);
// generic group bars 512+g*64 / +32; XCNT 1024+x*32; LIN 1280;
// rendezvous RCNT 1312, RREL 1344.
#define BAR_XCNT 1024
#define BAR_LIN  1280
#define BAR_RCNT 1312
#define BAR_RREL 1344

// device-wide rendezvous (agent scope, one-shot) — round-4-proven pattern.
__device__ __forceinline__ void devbar(unsigned* cnt, unsigned* rel) {
  __syncthreads();
  if (threadIdx.x == 0) {
    unsigned prev = __hip_atomic_fetch_add(cnt, 1u, __ATOMIC_RELAXED,
                                           __HIP_MEMORY_SCOPE_AGENT);
    if (prev == 255u)
      __hip_atomic_store(rel, 1u, __ATOMIC_RELAXED, __HIP_MEMORY_SCOPE_AGENT);
    while (__hip_atomic_load(rel, __ATOMIC_RELAXED,
                             __HIP_MEMORY_SCOPE_AGENT) == 0u)
      __builtin_amdgcn_s_sleep(2);
  }
  __syncthreads();
  asm volatile("" ::: "memory");
}

// intra-group barrier (32 blocks). MODE 0: all L2-local workgroup-scope RMWs
// (rel low 16 bits = release count; spin adds 0x10000 so the RMW is never
// idempotent-optimized into a cacheable load) + per-CU buffer_inv acquire.
// MODE 1: agent-scope (round-4 semantics).
template <int MODE>
__device__ __forceinline__ void grpbar(unsigned* cnt, unsigned* rel,
                                       unsigned gen) {
  __syncthreads();
  if (threadIdx.x == 0) {
    if (MODE == 0) {
      unsigned prev = __hip_atomic_fetch_add(cnt, 1u, __ATOMIC_RELAXED,
                                             __HIP_MEMORY_SCOPE_WORKGROUP);
      if (prev == gen * 32u - 1u)
        (void)__hip_atomic_fetch_add(rel, 1u, __ATOMIC_RELAXED,
                                     __HIP_MEMORY_SCOPE_WORKGROUP);
      while ((__hip_atomic_fetch_add(rel, 0x10000u, __ATOMIC_RELAXED,
                                     __HIP_MEMORY_SCOPE_WORKGROUP) &
              0xFFFFu) < gen)
        __builtin_amdgcn_s_sleep(1);
      asm volatile("buffer_inv\n\ts_waitcnt vmcnt(0)" ::: "memory");
    } else {
      unsigned prev = __hip_atomic_fetch_add(cnt, 1u, __ATOMIC_RELAXED,
                                             __HIP_MEMORY_SCOPE_AGENT);
      if (prev == gen * 32u - 1u)
        __hip_atomic_store(rel, gen, __ATOMIC_RELAXED,
                           __HIP_MEMORY_SCOPE_AGENT);
      while (__hip_atomic_load(rel, __ATOMIC_RELAXED,
                               __HIP_MEMORY_SCOPE_AGENT) < gen)
        __builtin_amdgcn_s_sleep(1);
    }
  }
  __syncthreads();
  asm volatile("" ::: "memory");
}

// fill h_lds[16][260] from a global [16][256] buffer (1024 thr, 1 float4 ea)
template <int MODE>
__device__ __forceinline__ void fill_h(float* h_lds, const float* src,
                                       const int tid) {
  const int r = tid >> 6, c4 = (tid & 63) * 4;
  float4 v = Acc<MODE>::ld4(src + r * 256 + c4);
  *(float4*)&h_lds[r * 260 + c4] = v;
}

// q stage: xm[r][n] = 2*sig(hm_row . qW[n] + qb[n]) * xsrc; n-slice of 128
// per block; 8 threads per n (interleaved k so LDS reads are conflict-free).
template <typename ZT, int MODE>
__device__ __forceinline__ void q_stage(
    const float* qW, const float* qb, const int sflag, const int t,
    const ZT* zz, float* xm, const float* h_lds, const int rank,
    const int row0, const int tid)
{
  using A = Acc<MODE>;
  const int nl = tid >> 3, sub = tid & 7;
  const int n = rank * 128 + nl;
  const float* wrow = qW + (size_t)n * 256;
  float acc[16];
#pragma unroll
  for (int r = 0; r < 16; ++r) acc[r] = 0.f;
#pragma unroll
  for (int kk = 0; kk < 8; ++kk) {
    const int ko = kk * 32 + sub * 4;
    float4 w = *(const float4*)(wrow + ko);
#pragma unroll
    for (int r = 0; r < 16; ++r) {
      float4 hv = *(const float4*)&h_lds[r * 260 + ko];
      acc[r] += w.x * hv.x + w.y * hv.y + w.z * hv.z + w.w * hv.w;
    }
  }
#pragma unroll
  for (int r = 0; r < 16; ++r) {
    acc[r] += __shfl_xor(acc[r], 4);
    acc[r] += __shfl_xor(acc[r], 2);
    acc[r] += __shfl_xor(acc[r], 1);
  }
  const float bias = qb[n];
  const int rb = sub * 2;
#pragma unroll
  for (int rr = 0; rr < 2; ++rr) {
    const int r = rb + rr;
    float xv;
    if (sflag == 0)
      xv = ld1(zz + (size_t)(row0 + r) * 524288 + (size_t)t * 4096 + n);
    else
      xv = A::ld(xm + r * 4096 + n);
    A::st(xm + r * 4096 + n, 2.0f * sigf(acc[r] + bias) * xv);
  }
}

// r stage: hm_out[r][n] = 2*sig(xm_row . rW[n] + rb[n]) * src[r][n].
// wave w: n = rank*8 + (w&7), rows (w>>3)*8..+8; full K=4096 per wave via
// 4 LDS slabs of [16][1024]; 64-lane k-split (coalesced weight loads).
template <int MODE>
__device__ __forceinline__ void r_stage(
    const float* rW, const float* rb, float* hm_out, const float* xm,
    const float* h_lds /*src*/, float* xm_lds, float* red, const int rank,
    const int tid, const int wv, const int ln)
{
  using A = Acc<MODE>;
  const int nj = wv & 7, rh = wv >> 3;
  const int n = rank * 8 + nj;
  const float* wr = rW + (size_t)n * 4096;
  float acc[8];
#pragma unroll
  for (int r = 0; r < 8; ++r) acc[r] = 0.f;
#pragma unroll 1
  for (int sl = 0; sl < 4; ++sl) {
    const int kb = sl * 1024;
    __syncthreads();
#pragma unroll
    for (int j = 0; j < 4; ++j) {
      const int f = tid + j * 1024;
      const int row = f >> 8, col = (f & 255) * 4;
      float4 v = A::ld4(xm + row * 4096 + kb + col);
      *(float4*)&xm_lds[row * 1032 + col] = v;
    }
    __syncthreads();
#pragma unroll
    for (int q4 = 0; q4 < 4; ++q4) {
      const int ko = q4 * 256 + ln * 4;
      float4 w = *(const float4*)(wr + kb + ko);
#pragma unroll
      for (int rr = 0; rr < 8; ++rr) {
        float4 xv = *(const float4*)&xm_lds[(rh * 8 + rr) * 1032 + ko];
        acc[rr] += w.x * xv.x + w.y * xv.y + w.z * xv.z + w.w * xv.w;
      }
    }
  }
#pragma unroll
  for (int rr = 0; rr < 8; ++rr) {
#pragma unroll
    for (int m = 32; m; m >>= 1) acc[rr] += __shfl_xor(acc[rr], m);
  }
  if (ln < 8) red[wv * 8 + ln] = acc[ln];
  __syncthreads();
  if (tid < 128) {
    const int nj2 = tid >> 4, r = tid & 15;
    const int n2 = rank * 8 + nj2;
    const float s = red[((r >> 3) * 8 + nj2) * 8 + (r & 7)];
    const float hv = 2.0f * sigf(s + rb[n2]) * h_lds[r * 260 + n2];
    A::st(hm_out + r * 256 + n2, hv);
  }
  __syncthreads();
}

// gates stage: gates[r][nj] = xm_row . wih[nj] + hm2_row . whh[nj]
// (biases added in hfin). wave w: nj pair rank*32 + 2w,+1; full K.
template <int MODE>
__device__ __forceinline__ void g_stage(
    const float* wih, const float* whh, float* gates, const float* xm,
    const float* h_lds /*hm2*/, float* xm_lds, const int rank, const int tid,
    const int wv, const int ln)
{
  using A = Acc<MODE>;
  const int njA = rank * 32 + wv * 2;
  const float* wA = wih + (size_t)njA * 4096;
  const float* wB = wA + 4096;
  float a0[16], a1[16];
#pragma unroll
  for (int r = 0; r < 16; ++r) { a0[r] = 0.f; a1[r] = 0.f; }
#pragma unroll 1
  for (int sl = 0; sl < 4; ++sl) {
    const int kb = sl * 1024;
    __syncthreads();
#pragma unroll
    for (int j = 0; j < 4; ++j) {
      const int f = tid + j * 1024;
      const int row = f >> 8, col = (f & 255) * 4;
      float4 v = A::ld4(xm + row * 4096 + kb + col);
      *(float4*)&xm_lds[row * 1032 + col] = v;
    }
    __syncthreads();
#pragma unroll
    for (int q4 = 0; q4 < 4; ++q4) {
      const int ko = q4 * 256 + ln * 4;
      float4 wa = *(const float4*)(wA + kb + ko);
      float4 wb = *(const float4*)(wB + kb + ko);
#pragma unroll
      for (int r = 0; r < 16; ++r) {
        float4 xv = *(const float4*)&xm_lds[r * 1032 + ko];
        a0[r] += wa.x * xv.x + wa.y * xv.y + wa.z * xv.z + wa.w * xv.w;
        a1[r] += wb.x * xv.x + wb.y * xv.y + wb.z * xv.z + wb.w * xv.w;
      }
    }
  }
  {  // whh part from h_lds (holds hm2), K=256 in one 64-lane pass
    const int ko = ln * 4;
    float4 wa = *(const float4*)(whh + (size_t)njA * 256 + ko);
    float4 wb = *(const float4*)(whh + (size_t)(njA + 1) * 256 + ko);
#pragma unroll
    for (int r = 0; r < 16; ++r) {
      float4 hv = *(const float4*)&h_lds[r * 260 + ko];
      a0[r] += wa.x * hv.x + wa.y * hv.y + wa.z * hv.z + wa.w * hv.w;
      a1[r] += wb.x * hv.x + wb.y * hv.y + wb.z * hv.z + wb.w * hv.w;
    }
  }
#pragma unroll
  for (int r = 0; r < 16; ++r) {
#pragma unroll
    for (int m = 32; m; m >>= 1) {
      a0[r] += __shfl_xor(a0[r], m);
      a1[r] += __shfl_xor(a1[r], m);
    }
  }
  if (ln < 16) {
    A::st(gates + ln * 1024 + njA, a0[ln]);
    A::st(gates + ln * 1024 + njA + 1, a1[ln]);
  }
}

template <typename ZT, int MODE>
__device__ void lstm_body(const LPar& p, const int grp, const int rank,
                          float* h_lds, float* c_lds, float* xm_lds,
                          float* red)
{
  using A = Acc<MODE>;
  float* gb    = p.grp + (size_t)grp * 131072;
  float* xm    = gb;
  float* hmA   = gb + 65536;
  float* hmB   = gb + 69632;
  float* hmC   = gb + 73728;
  float* gates = gb + 77824;
  unsigned* bcnt = p.bar + (MODE == 0 ? 0 : 512) + grp * 64;
  unsigned* brel = bcnt + 32;
  const int tid = threadIdx.x;
  const int wv = tid >> 6, ln = tid & 63;
  const int row0 = grp * 16;
  const ZT* zz = (const ZT*)p.z;
  unsigned gen = 0;

  for (int t = 0; t <= 128; ++t) {
    // ---- stage A: hfin (computed redundantly by every block; h,c in LDS) --
    if (t == 0) {
      for (int j = tid; j < 4096; j += 1024) {
        h_lds[(j >> 8) * 260 + (j & 255)] = 0.f;
        c_lds[j] = 0.f;
      }
    } else {
      for (int j = tid; j < 4096; j += 1024) {
        const int r = j >> 8, k = j & 255;
        const float* gr = gates + r * 1024 + k;
        float gi = A::ld(gr)       + p.bih[k]       + p.bhh[k];
        float gf = A::ld(gr + 256) + p.bih[k + 256] + p.bhh[k + 256];
        float gg = A::ld(gr + 512) + p.bih[k + 512] + p.bhh[k + 512];
        float go = A::ld(gr + 768) + p.bih[k + 768] + p.bhh[k + 768];
        float cn = sigf(gf) * c_lds[j] + sigf(gi) * tanhf(gg);
        c_lds[j] = cn;
        h_lds[r * 260 + k] = sigf(go) * tanhf(cn);
      }
    }
    __syncthreads();
    if (t == 128) break;

    // ---- A cont.: q0 (src=z, hm=h) ----
    q_stage<ZT, MODE>(p.qw0, p.qb0, 0, t, zz, xm, h_lds, rank, row0, tid);
    grpbar<MODE>(bcnt, brel, ++gen);
    // ---- B: r0 -> hmA (src=h) ----
    r_stage<MODE>(p.rw0, p.rb0, hmA, xm, h_lds, xm_lds, red, rank, tid, wv, ln);
    grpbar<MODE>(bcnt, brel, ++gen);
    // ---- C: q1 (hm=hmA, src=xm) ----
    fill_h<MODE>(h_lds, hmA, tid);
    __syncthreads();
    q_stage<ZT, MODE>(p.qw1, p.qb1, 1, t, zz, xm, h_lds, rank, row0, tid);
    grpbar<MODE>(bcnt, brel, ++gen);
    // ---- D: r1 -> hmB (src=hmA, still in h_lds) ----
    r_stage<MODE>(p.rw1, p.rb1, hmB, xm, h_lds, xm_lds, red, rank, tid, wv, ln);
    grpbar<MODE>(bcnt, brel, ++gen);
    // ---- E: q2 (hm=hmB, src=xm) ----
    fill_h<MODE>(h_lds, hmB, tid);
    __syncthreads();
    q_stage<ZT, MODE>(p.qw2, p.qb2, 1, t, zz, xm, h_lds, rank, row0, tid);
    grpbar<MODE>(bcnt, brel, ++gen);
    // ---- F: r2 -> hmC (src=hmB, still in h_lds) ----
    r_stage<MODE>(p.rw2, p.rb2, hmC, xm, h_lds, xm_lds, red, rank, tid, wv, ln);
    grpbar<MODE>(bcnt, brel, ++gen);
    // ---- G: gates = xm@wih^T + hmC@whh^T ----
    fill_h<MODE>(h_lds, hmC, tid);
    __syncthreads();
    g_stage<MODE>(p.wih, p.whh, gates, xm, h_lds, xm_lds, rank, tid, wv, ln);
    grpbar<MODE>(bcnt, brel, ++gen);
  }
  // ---- FC (rank 0 of each group; h is in LDS) ----
  if (rank == 0 && tid < 80) {
    const int r = tid / 5, j = tid % 5;
    float acc = p.fcb[j];
    const float* w = p.fcw + j * 256;
    const float* hr = &h_lds[r * 260];
    for (int k = 0; k < 256; ++k) acc += hr[k] * w[k];
    p.out[(size_t)(row0 + r) * 5 + j] = acc;
  }
}

// 256 blocks x 1024 threads; ~100KB static LDS forces 1 block/CU, so each
// XCD hosts exactly 32 blocks -> XCD-local groups are complete.
template <typename ZT>
__global__ __launch_bounds__(1024, 4) void k_lstm(LPar p)
{
  __shared__ float h_lds[16 * 260];
  __shared__ float c_lds[4096];
  __shared__ float xm_lds[16 * 1032];
  __shared__ float red[128];
  __shared__ unsigned s_meta[4];
  const int tid = threadIdx.x;

  if (tid == 0) {
    unsigned xcc;
    asm volatile("s_getreg_b32 %0, hwreg(HW_REG_XCC_ID)" : "=s"(xcc));
    xcc &= 7u;
    unsigned fr = __hip_atomic_fetch_add(p.bar + BAR_XCNT + xcc * 32, 1u,
                                         __ATOMIC_RELAXED,
                                         __HIP_MEMORY_SCOPE_AGENT);
    unsigned lr = __hip_atomic_fetch_add(p.bar + BAR_LIN, 1u,
                                         __ATOMIC_RELAXED,
                                         __HIP_MEMORY_SCOPE_AGENT);
    s_meta[0] = xcc; s_meta[1] = fr; s_meta[2] = lr;
  }
  __syncthreads();
  devbar(p.bar + BAR_RCNT, p.bar + BAR_RREL);
  if (tid == 0) {
    unsigned ok = 1u;
    for (int x = 0; x < 8; ++x)
      ok &= (__hip_atomic_load(p.bar + BAR_XCNT + x * 32, __ATOMIC_RELAXED,
                               __HIP_MEMORY_SCOPE_AGENT) == 32u) ? 1u : 0u;
    s_meta[3] = ok;
  }
  __syncthreads();
  if (s_meta[3]) {
    lstm_body<ZT, 0>(p, (int)s_meta[0], (int)(s_meta[1] & 31u),
                     h_lds, c_lds, xm_lds, red);
  } else {
    lstm_body<ZT, 1>(p, (int)(s_meta[2] >> 5), (int)(s_meta[2] & 31u),
                     h_lds, c_lds, xm_lds, red);
  }
}

// diagnostic: report ws_size (MiB) through the output if workspace too small
__global__ __launch_bounds__(256) void k_report(float* out, float v, int n) {
  int i = blockIdx.x * 256 + threadIdx.x;
  if (i < n) out[i] = v;
}

// ---------------------------------------------------------------------------
struct Net {
  const float *x;
  const float *c1a_w, *c1a_b, *g1a, *b1a, *m1a, *v1a;
  const float *c1b_w, *c1b_b, *g1b, *b1b, *m1b, *v1b;
  const float *c2a_w, *c2a_b, *g2a, *b2a, *m2a, *v2a;
  const float *c2b_w, *c2b_b, *g2b, *b2b, *m2b, *v2b;
  const float *qw[3], *qb[3], *rw[3], *rb[3];
  const float *wih, *whh, *bih, *bhh, *fcw, *fcb;
};

template <typename ZT>
static void run_all(const Net& p, ZT* z, u16* y1u, float* scr,
                    float* ps1, float* pss1, float* st1v,
                    float* ps2, float* pss2, float* st2v,
                    float* out, hipStream_t stream)
{
  float* grp = scr;                               // 8*131072 = 1,048,576 f
  unsigned* bar = (unsigned*)(scr + 1048576);     // barrier state

  k_conv1<<<dim3(128, 32), 256, 0, stream>>>(p.x, p.c1a_w, p.c1a_b, p.g1a,
      p.b1a, p.m1a, p.v1a, p.c1b_w, p.c1b_b, p.g1b, p.b1b, p.m1b, p.v1b,
      y1u, ps1, pss1);
  k_red<<<16, 256, 0, stream>>>(ps1, pss1, st1v, 32, 4096);
  k_simam_t<u16><<<4096, 256, 0, stream>>>(y1u, st1v, 4096);
  k_conv2<ZT><<<dim3(64, 128), 256, 0, stream>>>(y1u, p.c2a_w, p.c2a_b, p.g2a,
      p.b2a, p.m2a, p.v2a, p.c2b_w, p.c2b_b, p.g2b, p.b2b, p.m2b, p.v2b,
      z, ps2, pss2);
  k_red<<<32, 256, 0, stream>>>(ps2, pss2, st2v, 64, 8192);
  k_simam_t<ZT><<<8192, 256, 0, stream>>>(z, st2v, 8192);

  // barrier state lives in the y1u overlay region -> zero it only after the
  // CNN kernels (stream-ordered) are past their last y1u/scr use.
  hipMemsetAsync((void*)bar, 0, 8192, stream);

  LPar P;
  P.z = (const void*)z;
  P.qw0 = p.qw[0]; P.qb0 = p.qb[0]; P.rw0 = p.rw[0]; P.rb0 = p.rb[0];
  P.qw1 = p.qw[1]; P.qb1 = p.qb[1]; P.rw1 = p.rw[1]; P.rb1 = p.rb[1];
  P.qw2 = p.qw[2]; P.qb2 = p.qb[2]; P.rw2 = p.rw[2]; P.rb2 = p.rb[2];
  P.wih = p.wih; P.whh = p.whh; P.bih = p.bih; P.bhh = p.bhh;
  P.fcw = p.fcw; P.fcb = p.fcb;
  P.grp = grp; P.bar = bar; P.out = out;

  void* args[] = { (void*)&P };
  hipError_t e = hipLaunchCooperativeKernel(
      (const void*)k_lstm<ZT>, dim3(256), dim3(1024), args, 0, stream);
  if (e != hipSuccess) {
    (void)hipGetLastError();  // clear sticky error
    // ~100KB LDS/block => 1 block/CU; 256 blocks on 256 CUs are co-resident
    // even under a plain launch.
    k_lstm<ZT><<<dim3(256), dim3(1024), 0, stream>>>(P);
  }
}

extern "C" void kernel_launch(void* const* d_in, const int* in_sizes, int n_in,
                              void* d_out, int out_size, void* d_ws, size_t ws_size,
                              hipStream_t stream)
{
  (void)in_sizes; (void)n_in;
  Net p;
  p.x = (const float*)d_in[0];
  p.c1a_w = (const float*)d_in[1];  p.c1a_b = (const float*)d_in[2];
  p.g1a = (const float*)d_in[3];    p.b1a = (const float*)d_in[4];
  p.m1a = (const float*)d_in[5];    p.v1a = (const float*)d_in[6];
  p.c1b_w = (const float*)d_in[7];  p.c1b_b = (const float*)d_in[8];
  p.g1b = (const float*)d_in[9];    p.b1b = (const float*)d_in[10];
  p.m1b = (const float*)d_in[11];   p.v1b = (const float*)d_in[12];
  p.c2a_w = (const float*)d_in[13]; p.c2a_b = (const float*)d_in[14];
  p.g2a = (const float*)d_in[15];   p.b2a = (const float*)d_in[16];
  p.m2a = (const float*)d_in[17];   p.v2a = (const float*)d_in[18];
  p.c2b_w = (const float*)d_in[19]; p.c2b_b = (const float*)d_in[20];
  p.g2b = (const float*)d_in[21];   p.b2b = (const float*)d_in[22];
  p.m2b = (const float*)d_in[23];   p.v2b = (const float*)d_in[24];
  for (int i = 0; i < 3; ++i) {
    p.qw[i] = (const float*)d_in[25 + 4 * i];
    p.qb[i] = (const float*)d_in[26 + 4 * i];
    p.rw[i] = (const float*)d_in[27 + 4 * i];
    p.rb[i] = (const float*)d_in[28 + 4 * i];
  }
  p.wih = (const float*)d_in[37]; p.whh = (const float*)d_in[38];
  p.bih = (const float*)d_in[39]; p.bhh = (const float*)d_in[40];
  p.fcw = (const float*)d_in[41]; p.fcb = (const float*)d_in[42];
  float* out = (float*)d_out;
  char* base = (char*)d_ws;

  // z elems = 67,108,864 ; y1 elems = 33,554,432 ; stats block = 6,422,528 B
  const size_t ZB_F32 = 268435456, ZB_BF16 = 134217728, Y1B = 67108864;
  const size_t STATS = 1048576 * 2 + 65536 + 2097152 * 2 + 65536;
  const size_t HI_NEED = ZB_F32 + Y1B + STATS;   // ~326 MiB
  const size_t LO_NEED = ZB_BF16 + Y1B + STATS;  // ~198 MiB

  if (ws_size >= HI_NEED) {
    float* z = (float*)base;
    u16* y1u = (u16*)(base + ZB_F32);
    float* scr = (float*)(base + ZB_F32);  // overlays y1u after conv2 is done
    char* sb = base + ZB_F32 + Y1B;
    run_all<float>(p, z, y1u, scr,
                   (float*)sb, (float*)(sb + 1048576), (float*)(sb + 2097152),
                   (float*)(sb + 2162688), (float*)(sb + 4259840),
                   (float*)(sb + 6356992), out, stream);
  } else if (ws_size >= LO_NEED) {
    u16* z = (u16*)base;
    u16* y1u = (u16*)(base + ZB_BF16);
    float* scr = (float*)(base + ZB_BF16);  // overlays y1u after conv2 is done
    char* sb = base + ZB_BF16 + Y1B;
    run_all<u16>(p, z, y1u, scr,
                 (float*)sb, (float*)(sb + 1048576), (float*)(sb + 2097152),
                 (float*)(sb + 2162688), (float*)(sb + 4259840),
                 (float*)(sb + 6356992), out, stream);
  } else {
    k_report<<<3, 256, 0, stream>>>(out, (float)(ws_size >> 20), out_size);
  }
}